// Round 12
// baseline (519.584 us; speedup 1.0000x reference)
//
#include <hip/hip_runtime.h>
#include <hip/hip_bf16.h>
#include <hip/hip_fp16.h>

// GraphSAGE: 4x (mean-agg SAGEConv + ReLU) -> mean pool -> linear classifier
// N=50000, E=800000, dims 128->128->64. fp16 feature storage, fp32 accum,
// MFMA (16x16x32 f16) for the dual linear layers.
// CSR build: bucketed partition (no deg atomics) + per-bucket LDS histogram.
// Gather: 4x dim-slices of 64B (one full cache line; h rows 256B-aligned);
// slice = blockIdx&3 so each XCD (blockIdx%8 round-robin) touches one 3.2MB
// slice -> L2-resident.
// NOTE (round 8): 32B slices REGRESSED 2.2x (half-line fetch amplification);
// slices must be >= 64B line granularity.
// NOTE (round 10): linear with 16 rows/wave was B-load-bound -> 64 rows/wave.
// NOTE (round 11): random global deg atomics churn ~25MB of line writebacks.

typedef _Float16 f16x8 __attribute__((ext_vector_type(8)));
typedef float f32x4 __attribute__((ext_vector_type(4)));

// --- phase A: partition (tgt,src) pairs into 8 target-range buckets (dense
// staging). Wave-aggregated LDS counters; 512 edges/block for occupancy. ---
__global__ __launch_bounds__(256) void k_bucket(
    const int* __restrict__ src, const int* __restrict__ tgt,
    unsigned long long* __restrict__ staging,
    int* __restrict__ bucket_fill, int E, int bdiv, int cap) {
  __shared__ unsigned long long buf[8][96];
  __shared__ int cnt[8];
  __shared__ int base[8];
  int tid = threadIdx.x;
  int lane = tid & 63;
  if (tid < 8) cnt[tid] = 0;
  __syncthreads();
  int e0 = blockIdx.x * 512;
#pragma unroll
  for (int i = 0; i < 2; ++i) {
    int e = e0 + i * 256 + tid;
    int b = -1;
    unsigned long long pair = 0;
    if (e < E) {
      int t = tgt[e];
      int s = src[e];
      b = t / bdiv;
      pair = ((unsigned long long)(unsigned)t << 32) | (unsigned)s;
    }
#pragma unroll
    for (int bk = 0; bk < 8; ++bk) {
      bool mine = (b == bk);
      unsigned long long mask = __ballot(mine);
      if (mask == 0ull) continue;  // ballot is wave-uniform
      int cw = __popcll(mask);
      int leader = __ffsll((unsigned long long)mask) - 1;
      int p0 = 0;
      if (lane == leader) p0 = atomicAdd(&cnt[bk], cw);
      p0 = __shfl(p0, leader, 64);
      if (mine) {
        int p = p0 + __popcll(mask & ((1ull << lane) - 1ull));
        if (p < 96) {
          buf[bk][p] = pair;
        } else {  // rare overflow: reserve a global slot directly
          int gp = atomicAdd(&bucket_fill[bk], 1);
          staging[(size_t)bk * cap + gp] = pair;
        }
      }
    }
  }
  __syncthreads();
  if (tid < 8) {
    int c = min(cnt[tid], 96);
    base[tid] = atomicAdd(&bucket_fill[tid], c);
    cnt[tid] = c;
  }
  __syncthreads();
  for (int b = 0; b < 8; ++b) {
    int c = cnt[b];
    if (tid < c) staging[(size_t)b * cap + base[b] + tid] = buf[b][tid];
  }
}

// --- phase A2: per-bucket degree histogram in LDS (bucket spans <= bdiv
// nodes = 25KB); 8 sub-blocks per bucket, dense global merge. ---
__global__ __launch_bounds__(256) void k_hist(
    const unsigned long long* __restrict__ staging,
    const int* __restrict__ bucket_fill, int* __restrict__ deg,
    int bdiv, int cap, int n) {
  __shared__ int hist[8192];
  int tid = threadIdx.x;
  int bk = blockIdx.x & 7;
  int sub = blockIdx.x >> 3;
  int lo = bk * bdiv;
  int bsize = min(bdiv, n - lo);
  if (bsize <= 0) return;
  for (int j = tid; j < bsize; j += 256) hist[j] = 0;
  __syncthreads();
  int nb = bucket_fill[bk];
  const unsigned long long* sb = staging + (size_t)bk * cap;
  for (int i = sub * 256 + tid; i < nb; i += 8 * 256) {
    int t = (int)(sb[i] >> 32);
    atomicAdd(&hist[t - lo], 1);
  }
  __syncthreads();
  for (int j = tid; j < bsize; j += 256) {
    int v = hist[j];
    if (v) atomicAdd(&deg[lo + j], v);
  }
}

// --- phase B: per-bucket scatter; block g -> bucket g&7 (XCD-local writes) ---
__global__ __launch_bounds__(256) void k_scatter2(
    const unsigned long long* __restrict__ staging,
    const int* __restrict__ bucket_fill, int* __restrict__ cursor,
    int* __restrict__ csr_src, int cap) {
  int b = blockIdx.x & 7;
  int nchunk = gridDim.x >> 3;
  int chunk = blockIdx.x >> 3;
  int n = bucket_fill[b];
  const unsigned long long* sb = staging + (size_t)b * cap;
  for (int i0 = chunk * 2048; i0 < n; i0 += nchunk * 2048) {
#pragma unroll
    for (int t = 0; t < 8; ++t) {
      int i = i0 + t * 256 + (int)threadIdx.x;
      if (i < n) {
        unsigned long long pair = sb[i];
        int tg = (int)(pair >> 32);
        int s = (int)(pair & 0xffffffffu);
        int pos = atomicAdd(&cursor[tg], 1);
        csr_src[pos] = s;
      }
    }
  }
}

// --- parallel exclusive scan over deg[0..n) -> row_start, cursor, inv_deg ---
__global__ __launch_bounds__(256) void k_scan1(const int* __restrict__ deg,
                                               int* __restrict__ partial,
                                               int* __restrict__ blocksum,
                                               float* __restrict__ inv_deg, int n) {
  __shared__ int s[256];
  int tid = threadIdx.x;
  int i = blockIdx.x * 256 + tid;
  int v = (i < n) ? deg[i] : 0;
  s[tid] = v;
  __syncthreads();
  for (int off = 1; off < 256; off <<= 1) {
    int t = (tid >= off) ? s[tid - off] : 0;
    __syncthreads();
    s[tid] += t;
    __syncthreads();
  }
  if (i < n) {
    partial[i] = s[tid] - v;
    inv_deg[i] = 1.0f / fmaxf((float)v, 1.0f);
  }
  if (tid == 255) blocksum[blockIdx.x] = s[255];
}

__global__ __launch_bounds__(256) void k_scan2(int* __restrict__ blocksum, int nb) {
  __shared__ int s[256];
  int tid = threadIdx.x;
  int v = (tid < nb) ? blocksum[tid] : 0;
  s[tid] = v;
  __syncthreads();
  for (int off = 1; off < 256; off <<= 1) {
    int t = (tid >= off) ? s[tid - off] : 0;
    __syncthreads();
    s[tid] += t;
    __syncthreads();
  }
  if (tid < nb) blocksum[tid] = s[tid] - v;
}

__global__ __launch_bounds__(256) void k_scan3(const int* __restrict__ partial,
                                               const int* __restrict__ blocksum,
                                               int* __restrict__ row_start,
                                               int* __restrict__ cursor, int n, int E) {
  int i = blockIdx.x * 256 + threadIdx.x;
  if (i < n) {
    int r = partial[i] + blocksum[blockIdx.x];
    row_start[i] = r;
    cursor[i] = r;
  }
  if (i == 0) row_start[n] = E;
}

// x fp32 -> fp16, 8 elements/thread
__global__ __launch_bounds__(256) void k_cvt_x(const float* __restrict__ x,
                                               __half* __restrict__ xh, int total8) {
  int i = blockIdx.x * 256 + threadIdx.x;
  if (i >= total8) return;
  const float4* p = (const float4*)(x + (size_t)i * 8);
  float4 v0 = p[0], v1 = p[1];
  f16x8 o;
  o[0] = (_Float16)v0.x; o[1] = (_Float16)v0.y; o[2] = (_Float16)v0.z; o[3] = (_Float16)v0.w;
  o[4] = (_Float16)v1.x; o[5] = (_Float16)v1.y; o[6] = (_Float16)v1.z; o[7] = (_Float16)v1.w;
  *(f16x8*)(xh + (size_t)i * 8) = o;
}

struct WPack {
  const float* s[4];
  const float* n[4];
};

// Wt[layer][n][k] (k in [0,256): k<128 -> Ws[k][n], else Wn[k-128][n]), fp16
__global__ __launch_bounds__(256) void k_prep_w(WPack p, __half* __restrict__ Wt) {
  int l = blockIdx.y;
  int i = blockIdx.x * 256 + threadIdx.x;  // [0, 32768)
  int n = i >> 8;
  int k = i & 255;
  const float* W = (k < 128) ? p.s[l] : p.n[l];
  float v = W[(size_t)(k & 127) * 128 + n];
  Wt[(size_t)l * 32768 + (size_t)n * 256 + k] = __float2half(v);
}

// XCD-sliced gather, 64B slices. Block b: slice s=b&3 = dims [s*32,s*32+32)
// (exactly one 64B line per row), node=(b>>2)*4+wave. With blockIdx%8->XCD
// round-robin, XCD x only touches slice x&3 (3.2MB, L2-resident).
// Lane: slot=lane>>2 (16 edges in flight), (lane&3)*8 -> 8 dims (f16x8).
// Fold slots with shfl_xor(4,8,16,32); lanes 0..3 write contiguous 64B.
__global__ __launch_bounds__(256) void k_agg_h(
    const __half* __restrict__ h, const int* __restrict__ csr_src,
    const int* __restrict__ row_start, const float* __restrict__ inv_deg,
    __half* __restrict__ agg, int n_nodes) {
  int b = blockIdx.x;
  int s = b & 3;
  int node = (b >> 2) * 4 + ((int)threadIdx.x >> 6);
  int lane = threadIdx.x & 63;
  if (node >= n_nodes) return;
  int slot = lane >> 2;               // edge slot 0..15
  int doff = s * 32 + (lane & 3) * 8; // dims doff..doff+7
  int beg = row_start[node];
  int end = row_start[node + 1];
  float a0 = 0.f, a1 = 0.f, a2 = 0.f, a3 = 0.f;
  float a4 = 0.f, a5 = 0.f, a6 = 0.f, a7 = 0.f;
  int e = beg;
  for (; e + 16 <= end; e += 16) {
    int i0 = csr_src[e + slot];
    f16x8 v = *(const f16x8*)(h + (size_t)i0 * 128 + doff);
    a0 += (float)v[0];
    a1 += (float)v[1];
    a2 += (float)v[2];
    a3 += (float)v[3];
    a4 += (float)v[4];
    a5 += (float)v[5];
    a6 += (float)v[6];
    a7 += (float)v[7];
  }
  if (e + slot < end) {
    int i0 = csr_src[e + slot];
    f16x8 v = *(const f16x8*)(h + (size_t)i0 * 128 + doff);
    a0 += (float)v[0];
    a1 += (float)v[1];
    a2 += (float)v[2];
    a3 += (float)v[3];
    a4 += (float)v[4];
    a5 += (float)v[5];
    a6 += (float)v[6];
    a7 += (float)v[7];
  }
  // fold the 16 edge slots (lanes with equal lane&3 hold identical dims)
#pragma unroll
  for (int off = 4; off <= 32; off <<= 1) {
    a0 += __shfl_xor(a0, off, 64);
    a1 += __shfl_xor(a1, off, 64);
    a2 += __shfl_xor(a2, off, 64);
    a3 += __shfl_xor(a3, off, 64);
    a4 += __shfl_xor(a4, off, 64);
    a5 += __shfl_xor(a5, off, 64);
    a6 += __shfl_xor(a6, off, 64);
    a7 += __shfl_xor(a7, off, 64);
  }
  if (slot == 0) {
    float wgt = inv_deg[node];
    f16x8 r;
    r[0] = (_Float16)(a0 * wgt);
    r[1] = (_Float16)(a1 * wgt);
    r[2] = (_Float16)(a2 * wgt);
    r[3] = (_Float16)(a3 * wgt);
    r[4] = (_Float16)(a4 * wgt);
    r[5] = (_Float16)(a5 * wgt);
    r[6] = (_Float16)(a6 * wgt);
    r[7] = (_Float16)(a7 * wgt);
    *(f16x8*)(agg + (size_t)node * 128 + doff) = r;
  }
}

// out[m][n] = relu( h[m]@Ws + agg[m]@Wn + b ), K=256 via mfma_f32_16x16x32_f16.
// Block = 256 threads = 4 waves, 64 rows. Wave w owns col-quarter cq=w (32
// cols) and ALL 64 rows (4 row-tiles): per K-step 2 B-frags + 4 A-frags feed
// 8 MFMAs (B loads amortized 4x; each Wt row read by one wave per block).
__global__ __launch_bounds__(256) void k_linear_mfma(
    const __half* __restrict__ h, const __half* __restrict__ agg,
    const __half* __restrict__ Wt, const float* __restrict__ bias,
    __half* __restrict__ out, int n_nodes) {
  int tid = threadIdx.x;
  int cq = tid >> 6;  // wave -> col quarter
  int lane = tid & 63;
  int node0 = blockIdx.x * 64;
  int lr = lane & 15;
  int lg = lane >> 4;

  f32x4 acc[4][2];
#pragma unroll
  for (int rt = 0; rt < 4; ++rt)
#pragma unroll
    for (int ct = 0; ct < 2; ++ct) acc[rt][ct] = (f32x4){0.f, 0.f, 0.f, 0.f};

  const __half* hrow[4];
  const __half* grow[4];
#pragma unroll
  for (int rt = 0; rt < 4; ++rt) {
    int arow = node0 + rt * 16 + lr;
    if (arow >= n_nodes) arow = n_nodes - 1;
    hrow[rt] = h + (size_t)arow * 128;
    grow[rt] = agg + (size_t)arow * 128;
  }

#pragma unroll
  for (int ks = 0; ks < 8; ++ks) {
    int koff = (ks & 3) * 32 + lg * 8;
    int kb = ks * 32 + lg * 8;
    f16x8 b0 = *(const f16x8*)(Wt + (size_t)(cq * 32 + lr) * 256 + kb);
    f16x8 b1 = *(const f16x8*)(Wt + (size_t)(cq * 32 + 16 + lr) * 256 + kb);
#pragma unroll
    for (int rt = 0; rt < 4; ++rt) {
      f16x8 a = (ks < 4) ? *(const f16x8*)(hrow[rt] + koff)
                         : *(const f16x8*)(grow[rt] + koff);
      acc[rt][0] = __builtin_amdgcn_mfma_f32_16x16x32_f16(a, b0, acc[rt][0], 0, 0, 0);
      acc[rt][1] = __builtin_amdgcn_mfma_f32_16x16x32_f16(a, b1, acc[rt][1], 0, 0, 0);
    }
  }

#pragma unroll
  for (int ct = 0; ct < 2; ++ct) {
    int n_col = cq * 32 + ct * 16 + lr;
    float bv = bias[n_col];
#pragma unroll
    for (int rt = 0; rt < 4; ++rt) {
#pragma unroll
      for (int r = 0; r < 4; ++r) {
        int m = node0 + rt * 16 + lg * 4 + r;
        if (m < n_nodes)
          out[(size_t)m * 128 + n_col] = __float2half(fmaxf(acc[rt][ct][r] + bv, 0.f));
      }
    }
  }
}

// 256 blocks x 256 threads; wave w handles rows blk*4+w (stride 1024), lane owns
// 2 dims via half2; LDS reduce across the 4 waves -> partial[blk][128].
__global__ __launch_bounds__(256) void k_pool(const __half* __restrict__ h,
                                              float* __restrict__ partial, int n_nodes) {
  __shared__ float red[4][128];
  int tid = threadIdx.x;
  int lane = tid & 63;
  int w = tid >> 6;
  float a0 = 0.f, a1 = 0.f;
  for (int n = blockIdx.x * 4 + w; n < n_nodes; n += gridDim.x * 4) {
    float2 f = __half22float2(*(const __half2*)(h + (size_t)n * 128 + lane * 2));
    a0 += f.x;
    a1 += f.y;
  }
  red[w][lane * 2] = a0;
  red[w][lane * 2 + 1] = a1;
  __syncthreads();
  if (tid < 128) {
    partial[(size_t)blockIdx.x * 128 + tid] =
        (red[0][tid] + red[1][tid]) + (red[2][tid] + red[3][tid]);
  }
}

// 512 threads: chunked parallel reduce of partial[256][128] -> g[128], then
// chunked classifier dot g@Wc[128][64] + bc. Max serial chain: 64 loads.
__global__ __launch_bounds__(512) void k_final(const float* __restrict__ partial,
                                               const float* __restrict__ Wc,
                                               const float* __restrict__ bc,
                                               float* __restrict__ out, int n_nodes) {
  __shared__ float red[4][128];
  __shared__ float gs[128];
  __shared__ float red2[8][64];
  int tid = threadIdx.x;
  int j = tid & 127;
  int c = tid >> 7;  // 4 chunks of 64 partials
  float s = 0.f;
#pragma unroll
  for (int b = 0; b < 64; ++b) s += partial[(size_t)(c * 64 + b) * 128 + j];
  red[c][j] = s;
  __syncthreads();
  if (tid < 128) {
    float g = (red[0][tid] + red[1][tid]) + (red[2][tid] + red[3][tid]);
    gs[tid] = g / (float)n_nodes;
  }
  __syncthreads();
  {
    int jo = tid & 63;
    int c2 = tid >> 6;  // 8 chunks of 16 k
    float s2 = 0.f;
#pragma unroll
    for (int d = 0; d < 16; ++d)
      s2 += gs[c2 * 16 + d] * Wc[(size_t)(c2 * 16 + d) * 64 + jo];
    red2[c2][jo] = s2;
  }
  __syncthreads();
  if (tid < 64) {
    float o = bc[tid];
#pragma unroll
    for (int c2 = 0; c2 < 8; ++c2) o += red2[c2][tid];
    out[tid] = o;
  }
}

extern "C" void kernel_launch(void* const* d_in, const int* in_sizes, int n_in,
                              void* d_out, int out_size, void* d_ws, size_t ws_size,
                              hipStream_t stream) {
  const float* x = (const float*)d_in[0];
  const int* ei = (const int*)d_in[1];
  const float* Ws11 = (const float*)d_in[2];
  const float* Wn11 = (const float*)d_in[3];
  const float* b11 = (const float*)d_in[4];
  const float* Ws12 = (const float*)d_in[5];
  const float* Wn12 = (const float*)d_in[6];
  const float* b12 = (const float*)d_in[7];
  const float* Ws21 = (const float*)d_in[8];
  const float* Wn21 = (const float*)d_in[9];
  const float* b21 = (const float*)d_in[10];
  const float* Ws22 = (const float*)d_in[11];
  const float* Wn22 = (const float*)d_in[12];
  const float* b22 = (const float*)d_in[13];
  const float* Wc = (const float*)d_in[14];
  const float* bc = (const float*)d_in[15];

  int N = in_sizes[0] / 128;
  int E = in_sizes[1] / 2;
  const int* src = ei;
  const int* tgt = ei + E;

  int bdiv = (N + 7) / 8;        // bucket = tgt / bdiv, 0..7 (bdiv <= 8192)
  int cap = E / 8 + 8192;        // per-bucket staging capacity

  // workspace layout (256B-aligned chunks)
  char* w = (char*)d_ws;
  size_t off = 0;
  auto alloc = [&](size_t bytes) {
    void* p = w + off;
    off += (bytes + 255) & ~(size_t)255;
    return p;
  };
  __half* xh = (__half*)alloc((size_t)N * 128 * 2);
  __half* hA = (__half*)alloc((size_t)N * 128 * 2);
  __half* hB = (__half*)alloc((size_t)N * 128 * 2);
  __half* aggb = (__half*)alloc((size_t)N * 128 * 2);
  __half* Wt = (__half*)alloc((size_t)4 * 32768 * 2);
  float* partial = (float*)alloc((size_t)256 * 128 * 4);
  float* inv_deg = (float*)alloc((size_t)N * 4);
  int* deg = (int*)alloc((size_t)N * 4);
  int* row_start = (int*)alloc((size_t)(N + 1) * 4);
  int* cursor = (int*)alloc((size_t)N * 4);
  int* csr_src = (int*)alloc((size_t)E * 4);
  int* scanp = (int*)alloc((size_t)N * 4);
  int* blocksum = (int*)alloc((size_t)256 * 4);
  unsigned long long* staging =
      (unsigned long long*)alloc((size_t)8 * cap * 8);
  int* bucket_fill = (int*)alloc((size_t)8 * 4);

  hipMemsetAsync(deg, 0, (size_t)N * 4, stream);
  hipMemsetAsync(bucket_fill, 0, 8 * 4, stream);
  hipMemsetAsync(partial, 0, (size_t)256 * 128 * 4, stream);

  int nb = (N + 255) / 256;
  int bb = (E + 511) / 512;
  k_bucket<<<bb, 256, 0, stream>>>(src, tgt, staging, bucket_fill, E, bdiv, cap);
  k_hist<<<64, 256, 0, stream>>>(staging, bucket_fill, deg, bdiv, cap, N);
  k_scan1<<<nb, 256, 0, stream>>>(deg, scanp, blocksum, inv_deg, N);
  k_scan2<<<1, 256, 0, stream>>>(blocksum, nb);
  k_scan3<<<nb, 256, 0, stream>>>(scanp, blocksum, row_start, cursor, N, E);
  k_scatter2<<<448, 256, 0, stream>>>(staging, bucket_fill, cursor, csr_src, cap);

  int total8 = N * 128 / 8;
  k_cvt_x<<<(total8 + 255) / 256, 256, 0, stream>>>(x, xh, total8);
  WPack wp;
  wp.s[0] = Ws11; wp.s[1] = Ws12; wp.s[2] = Ws21; wp.s[3] = Ws22;
  wp.n[0] = Wn11; wp.n[1] = Wn12; wp.n[2] = Wn21; wp.n[3] = Wn22;
  k_prep_w<<<dim3(128, 4), 256, 0, stream>>>(wp, Wt);

  int ab = 4 * ((N + 3) / 4);  // k_agg_h: 4 slices x (4 nodes/block)
  int lb = (N + 63) / 64;      // k_linear_mfma: 64 rows/block

  // layer 1: xh -> hA
  k_agg_h<<<ab, 256, 0, stream>>>(xh, csr_src, row_start, inv_deg, aggb, N);
  k_linear_mfma<<<lb, 256, 0, stream>>>(xh, aggb, Wt + 0 * 32768, b11, hA, N);
  // layer 2: hA -> hB
  k_agg_h<<<ab, 256, 0, stream>>>(hA, csr_src, row_start, inv_deg, aggb, N);
  k_linear_mfma<<<lb, 256, 0, stream>>>(hA, aggb, Wt + 1 * 32768, b12, hB, N);
  // layer 3: hB -> hA
  k_agg_h<<<ab, 256, 0, stream>>>(hB, csr_src, row_start, inv_deg, aggb, N);
  k_linear_mfma<<<lb, 256, 0, stream>>>(hB, aggb, Wt + 2 * 32768, b21, hA, N);
  // layer 4: hA -> hB
  k_agg_h<<<ab, 256, 0, stream>>>(hA, csr_src, row_start, inv_deg, aggb, N);
  k_linear_mfma<<<lb, 256, 0, stream>>>(hA, aggb, Wt + 3 * 32768, b22, hB, N);

  k_pool<<<256, 256, 0, stream>>>(hB, partial, N);
  k_final<<<1, 512, 0, stream>>>(partial, Wc, bc, (float*)d_out, N);
}

// Round 13
// 358.057 us; speedup vs baseline: 1.4511x; 1.4511x over previous
//
#include <hip/hip_runtime.h>
#include <hip/hip_bf16.h>
#include <hip/hip_fp16.h>

// GraphSAGE: 4x (mean-agg SAGEConv + ReLU) -> mean pool -> linear classifier
// N=50000, E=800000, dims 128->128->64. fp16 feature storage, fp32 accum,
// MFMA (16x16x32 f16) for the dual linear layers.
// CSR build: bucketed two-phase scatter (random 4B scatters cost a 64B line
// writeback each; bucketing by target range makes writes line-dense).
// NOTE (rounds 8+12): XCD dim-sliced gathers regressed/neutral BOTH times —
// fetch did not drop (blockIdx%8->XCD locality gives no L2 residency here).
// Gather is L3-bound at ~38us/layer; keep full-row, one wave per node.
// NOTE (round 10): linear with 16 rows/wave was B-load-bound -> 64 rows/wave.
// NOTE (round 12): partition-only bucket + separate hist cost +20us net;
// keep deg atomics inline in k_bucket. Round 13: chunk 2048->512 (391->1563
// blocks; occupancy was 13% at 1.5 blocks/CU).

typedef _Float16 f16x8 __attribute__((ext_vector_type(8)));
typedef float f32x4 __attribute__((ext_vector_type(4)));

// --- phase A: deg histogram + bucket (tgt,src) pairs into dense staging.
// Wave-aggregated LDS counters: 8 ballots/wave, 1 leader atomic per bucket
// per wave. 512 edges/block -> 1563 blocks (~6/CU) to hide atomic latency.
__global__ __launch_bounds__(256) void k_bucket(
    const int* __restrict__ src, const int* __restrict__ tgt,
    int* __restrict__ deg, unsigned long long* __restrict__ staging,
    int* __restrict__ bucket_fill, int E, int bdiv, int cap) {
  __shared__ unsigned long long buf[8][96];
  __shared__ int cnt[8];
  __shared__ int base[8];
  int tid = threadIdx.x;
  int lane = tid & 63;
  if (tid < 8) cnt[tid] = 0;
  __syncthreads();
  int e0 = blockIdx.x * 512;
#pragma unroll
  for (int i = 0; i < 2; ++i) {
    int e = e0 + i * 256 + tid;
    int b = -1;
    unsigned long long pair = 0;
    if (e < E) {
      int t = tgt[e];
      int s = src[e];
      atomicAdd(&deg[t], 1);
      b = t / bdiv;
      pair = ((unsigned long long)(unsigned)t << 32) | (unsigned)s;
    }
#pragma unroll
    for (int bk = 0; bk < 8; ++bk) {
      bool mine = (b == bk);
      unsigned long long mask = __ballot(mine);
      if (mask == 0ull) continue;  // ballot is wave-uniform
      int cw = __popcll(mask);
      int leader = __ffsll((unsigned long long)mask) - 1;
      int p0 = 0;
      if (lane == leader) p0 = atomicAdd(&cnt[bk], cw);
      p0 = __shfl(p0, leader, 64);
      if (mine) {
        int p = p0 + __popcll(mask & ((1ull << lane) - 1ull));
        if (p < 96) {
          buf[bk][p] = pair;
        } else {  // rare overflow: reserve a global slot directly
          int gp = atomicAdd(&bucket_fill[bk], 1);
          staging[(size_t)bk * cap + gp] = pair;
        }
      }
    }
  }
  __syncthreads();
  if (tid < 8) {
    int c = min(cnt[tid], 96);
    base[tid] = atomicAdd(&bucket_fill[tid], c);
    cnt[tid] = c;
  }
  __syncthreads();
  for (int b = 0; b < 8; ++b) {
    int c = cnt[b];
    if (tid < c) staging[(size_t)b * cap + base[b] + tid] = buf[b][tid];
  }
}

// --- phase B: per-bucket scatter; block g -> bucket g&7 (bucket-local writes) ---
__global__ __launch_bounds__(256) void k_scatter2(
    const unsigned long long* __restrict__ staging,
    const int* __restrict__ bucket_fill, int* __restrict__ cursor,
    int* __restrict__ csr_src, int cap) {
  int b = blockIdx.x & 7;
  int nchunk = gridDim.x >> 3;
  int chunk = blockIdx.x >> 3;
  int n = bucket_fill[b];
  const unsigned long long* sb = staging + (size_t)b * cap;
  for (int i0 = chunk * 2048; i0 < n; i0 += nchunk * 2048) {
#pragma unroll
    for (int t = 0; t < 8; ++t) {
      int i = i0 + t * 256 + (int)threadIdx.x;
      if (i < n) {
        unsigned long long pair = sb[i];
        int tg = (int)(pair >> 32);
        int s = (int)(pair & 0xffffffffu);
        int pos = atomicAdd(&cursor[tg], 1);
        csr_src[pos] = s;
      }
    }
  }
}

// --- parallel exclusive scan over deg[0..n) -> row_start, cursor, inv_deg ---
__global__ __launch_bounds__(256) void k_scan1(const int* __restrict__ deg,
                                               int* __restrict__ partial,
                                               int* __restrict__ blocksum,
                                               float* __restrict__ inv_deg, int n) {
  __shared__ int s[256];
  int tid = threadIdx.x;
  int i = blockIdx.x * 256 + tid;
  int v = (i < n) ? deg[i] : 0;
  s[tid] = v;
  __syncthreads();
  for (int off = 1; off < 256; off <<= 1) {
    int t = (tid >= off) ? s[tid - off] : 0;
    __syncthreads();
    s[tid] += t;
    __syncthreads();
  }
  if (i < n) {
    partial[i] = s[tid] - v;
    inv_deg[i] = 1.0f / fmaxf((float)v, 1.0f);
  }
  if (tid == 255) blocksum[blockIdx.x] = s[255];
}

__global__ __launch_bounds__(256) void k_scan2(int* __restrict__ blocksum, int nb) {
  __shared__ int s[256];
  int tid = threadIdx.x;
  int v = (tid < nb) ? blocksum[tid] : 0;
  s[tid] = v;
  __syncthreads();
  for (int off = 1; off < 256; off <<= 1) {
    int t = (tid >= off) ? s[tid - off] : 0;
    __syncthreads();
    s[tid] += t;
    __syncthreads();
  }
  if (tid < nb) blocksum[tid] = s[tid] - v;
}

__global__ __launch_bounds__(256) void k_scan3(const int* __restrict__ partial,
                                               const int* __restrict__ blocksum,
                                               int* __restrict__ row_start,
                                               int* __restrict__ cursor, int n, int E) {
  int i = blockIdx.x * 256 + threadIdx.x;
  if (i < n) {
    int r = partial[i] + blocksum[blockIdx.x];
    row_start[i] = r;
    cursor[i] = r;
  }
  if (i == 0) row_start[n] = E;
}

// x fp32 -> fp16, 8 elements/thread
__global__ __launch_bounds__(256) void k_cvt_x(const float* __restrict__ x,
                                               __half* __restrict__ xh, int total8) {
  int i = blockIdx.x * 256 + threadIdx.x;
  if (i >= total8) return;
  const float4* p = (const float4*)(x + (size_t)i * 8);
  float4 v0 = p[0], v1 = p[1];
  f16x8 o;
  o[0] = (_Float16)v0.x; o[1] = (_Float16)v0.y; o[2] = (_Float16)v0.z; o[3] = (_Float16)v0.w;
  o[4] = (_Float16)v1.x; o[5] = (_Float16)v1.y; o[6] = (_Float16)v1.z; o[7] = (_Float16)v1.w;
  *(f16x8*)(xh + (size_t)i * 8) = o;
}

struct WPack {
  const float* s[4];
  const float* n[4];
};

// Wt[layer][n][k] (k in [0,256): k<128 -> Ws[k][n], else Wn[k-128][n]), fp16
__global__ __launch_bounds__(256) void k_prep_w(WPack p, __half* __restrict__ Wt) {
  int l = blockIdx.y;
  int i = blockIdx.x * 256 + threadIdx.x;  // [0, 32768)
  int n = i >> 8;
  int k = i & 255;
  const float* W = (k < 128) ? p.s[l] : p.n[l];
  float v = W[(size_t)(k & 127) * 128 + n];
  Wt[(size_t)l * 32768 + (size_t)n * 256 + k] = __float2half(v);
}

// One wave per node. q=lane>>4 selects edge-in-group-of-4; lane&15 selects 8
// dims (f16x8 = 16B/lane -> one 256B row per 16-lane group). Main loop covers
// 16 edges -> 8 row loads in flight per lane; tails of 8/4/1.
// Fold q-groups with shfl_xor(16,32); fp32 accumulation throughout.
__global__ __launch_bounds__(256) void k_agg_h(
    const __half* __restrict__ h, const int* __restrict__ csr_src,
    const int* __restrict__ row_start, const float* __restrict__ inv_deg,
    __half* __restrict__ agg, int n_nodes) {
  int gw = (blockIdx.x * 256 + (int)threadIdx.x) >> 6;
  int lane = threadIdx.x & 63;
  if (gw >= n_nodes) return;
  int q = lane >> 4;         // edge slot 0..3
  int dl = (lane & 15) * 8;  // dims dl..dl+7
  int beg = row_start[gw];
  int end = row_start[gw + 1];
  float a0 = 0.f, a1 = 0.f, a2 = 0.f, a3 = 0.f;
  float a4 = 0.f, a5 = 0.f, a6 = 0.f, a7 = 0.f;
  int e = beg;
  for (; e + 16 <= end; e += 16) {
    int i0 = csr_src[e + q];
    int i1 = csr_src[e + 4 + q];
    int i2 = csr_src[e + 8 + q];
    int i3 = csr_src[e + 12 + q];
    f16x8 v0 = *(const f16x8*)(h + (size_t)i0 * 128 + dl);
    f16x8 v1 = *(const f16x8*)(h + (size_t)i1 * 128 + dl);
    f16x8 v2 = *(const f16x8*)(h + (size_t)i2 * 128 + dl);
    f16x8 v3 = *(const f16x8*)(h + (size_t)i3 * 128 + dl);
    a0 += ((float)v0[0] + (float)v1[0]) + ((float)v2[0] + (float)v3[0]);
    a1 += ((float)v0[1] + (float)v1[1]) + ((float)v2[1] + (float)v3[1]);
    a2 += ((float)v0[2] + (float)v1[2]) + ((float)v2[2] + (float)v3[2]);
    a3 += ((float)v0[3] + (float)v1[3]) + ((float)v2[3] + (float)v3[3]);
    a4 += ((float)v0[4] + (float)v1[4]) + ((float)v2[4] + (float)v3[4]);
    a5 += ((float)v0[5] + (float)v1[5]) + ((float)v2[5] + (float)v3[5]);
    a6 += ((float)v0[6] + (float)v1[6]) + ((float)v2[6] + (float)v3[6]);
    a7 += ((float)v0[7] + (float)v1[7]) + ((float)v2[7] + (float)v3[7]);
  }
  for (; e + 8 <= end; e += 8) {
    int i0 = csr_src[e + q];
    int i1 = csr_src[e + 4 + q];
    f16x8 v0 = *(const f16x8*)(h + (size_t)i0 * 128 + dl);
    f16x8 v1 = *(const f16x8*)(h + (size_t)i1 * 128 + dl);
    a0 += (float)v0[0] + (float)v1[0];
    a1 += (float)v0[1] + (float)v1[1];
    a2 += (float)v0[2] + (float)v1[2];
    a3 += (float)v0[3] + (float)v1[3];
    a4 += (float)v0[4] + (float)v1[4];
    a5 += (float)v0[5] + (float)v1[5];
    a6 += (float)v0[6] + (float)v1[6];
    a7 += (float)v0[7] + (float)v1[7];
  }
  for (; e + 4 <= end; e += 4) {
    int i0 = csr_src[e + q];
    f16x8 v0 = *(const f16x8*)(h + (size_t)i0 * 128 + dl);
    a0 += (float)v0[0];
    a1 += (float)v0[1];
    a2 += (float)v0[2];
    a3 += (float)v0[3];
    a4 += (float)v0[4];
    a5 += (float)v0[5];
    a6 += (float)v0[6];
    a7 += (float)v0[7];
  }
  if (e + q < end) {
    int i0 = csr_src[e + q];
    f16x8 v0 = *(const f16x8*)(h + (size_t)i0 * 128 + dl);
    a0 += (float)v0[0];
    a1 += (float)v0[1];
    a2 += (float)v0[2];
    a3 += (float)v0[3];
    a4 += (float)v0[4];
    a5 += (float)v0[5];
    a6 += (float)v0[6];
    a7 += (float)v0[7];
  }
  // fold the 4 edge slots (16-lane groups hold identical dim ranges)
  a0 += __shfl_xor(a0, 16, 64);
  a1 += __shfl_xor(a1, 16, 64);
  a2 += __shfl_xor(a2, 16, 64);
  a3 += __shfl_xor(a3, 16, 64);
  a4 += __shfl_xor(a4, 16, 64);
  a5 += __shfl_xor(a5, 16, 64);
  a6 += __shfl_xor(a6, 16, 64);
  a7 += __shfl_xor(a7, 16, 64);
  a0 += __shfl_xor(a0, 32, 64);
  a1 += __shfl_xor(a1, 32, 64);
  a2 += __shfl_xor(a2, 32, 64);
  a3 += __shfl_xor(a3, 32, 64);
  a4 += __shfl_xor(a4, 32, 64);
  a5 += __shfl_xor(a5, 32, 64);
  a6 += __shfl_xor(a6, 32, 64);
  a7 += __shfl_xor(a7, 32, 64);
  if (q == 0) {
    float wgt = inv_deg[gw];
    f16x8 r;
    r[0] = (_Float16)(a0 * wgt);
    r[1] = (_Float16)(a1 * wgt);
    r[2] = (_Float16)(a2 * wgt);
    r[3] = (_Float16)(a3 * wgt);
    r[4] = (_Float16)(a4 * wgt);
    r[5] = (_Float16)(a5 * wgt);
    r[6] = (_Float16)(a6 * wgt);
    r[7] = (_Float16)(a7 * wgt);
    *(f16x8*)(agg + (size_t)gw * 128 + dl) = r;
  }
}

// out[m][n] = relu( h[m]@Ws + agg[m]@Wn + b ), K=256 via mfma_f32_16x16x32_f16.
// Block = 256 threads = 4 waves, 64 rows. Wave w owns col-quarter cq=w (32
// cols) and ALL 64 rows (4 row-tiles): per K-step 2 B-frags + 4 A-frags feed
// 8 MFMAs (B loads amortized 4x; each Wt row read by one wave per block).
__global__ __launch_bounds__(256) void k_linear_mfma(
    const __half* __restrict__ h, const __half* __restrict__ agg,
    const __half* __restrict__ Wt, const float* __restrict__ bias,
    __half* __restrict__ out, int n_nodes) {
  int tid = threadIdx.x;
  int cq = tid >> 6;  // wave -> col quarter
  int lane = tid & 63;
  int node0 = blockIdx.x * 64;
  int lr = lane & 15;
  int lg = lane >> 4;

  f32x4 acc[4][2];
#pragma unroll
  for (int rt = 0; rt < 4; ++rt)
#pragma unroll
    for (int ct = 0; ct < 2; ++ct) acc[rt][ct] = (f32x4){0.f, 0.f, 0.f, 0.f};

  const __half* hrow[4];
  const __half* grow[4];
#pragma unroll
  for (int rt = 0; rt < 4; ++rt) {
    int arow = node0 + rt * 16 + lr;
    if (arow >= n_nodes) arow = n_nodes - 1;
    hrow[rt] = h + (size_t)arow * 128;
    grow[rt] = agg + (size_t)arow * 128;
  }

#pragma unroll
  for (int ks = 0; ks < 8; ++ks) {
    int koff = (ks & 3) * 32 + lg * 8;
    int kb = ks * 32 + lg * 8;
    f16x8 b0 = *(const f16x8*)(Wt + (size_t)(cq * 32 + lr) * 256 + kb);
    f16x8 b1 = *(const f16x8*)(Wt + (size_t)(cq * 32 + 16 + lr) * 256 + kb);
#pragma unroll
    for (int rt = 0; rt < 4; ++rt) {
      f16x8 a = (ks < 4) ? *(const f16x8*)(hrow[rt] + koff)
                         : *(const f16x8*)(grow[rt] + koff);
      acc[rt][0] = __builtin_amdgcn_mfma_f32_16x16x32_f16(a, b0, acc[rt][0], 0, 0, 0);
      acc[rt][1] = __builtin_amdgcn_mfma_f32_16x16x32_f16(a, b1, acc[rt][1], 0, 0, 0);
    }
  }

#pragma unroll
  for (int ct = 0; ct < 2; ++ct) {
    int n_col = cq * 32 + ct * 16 + lr;
    float bv = bias[n_col];
#pragma unroll
    for (int rt = 0; rt < 4; ++rt) {
#pragma unroll
      for (int r = 0; r < 4; ++r) {
        int m = node0 + rt * 16 + lg * 4 + r;
        if (m < n_nodes)
          out[(size_t)m * 128 + n_col] = __float2half(fmaxf(acc[rt][ct][r] + bv, 0.f));
      }
    }
  }
}

// 256 blocks x 256 threads; wave w handles rows blk*4+w (stride 1024), lane owns
// 2 dims via half2; LDS reduce across the 4 waves -> partial[blk][128].
__global__ __launch_bounds__(256) void k_pool(const __half* __restrict__ h,
                                              float* __restrict__ partial, int n_nodes) {
  __shared__ float red[4][128];
  int tid = threadIdx.x;
  int lane = tid & 63;
  int w = tid >> 6;
  float a0 = 0.f, a1 = 0.f;
  for (int n = blockIdx.x * 4 + w; n < n_nodes; n += gridDim.x * 4) {
    float2 f = __half22float2(*(const __half2*)(h + (size_t)n * 128 + lane * 2));
    a0 += f.x;
    a1 += f.y;
  }
  red[w][lane * 2] = a0;
  red[w][lane * 2 + 1] = a1;
  __syncthreads();
  if (tid < 128) {
    partial[(size_t)blockIdx.x * 128 + tid] =
        (red[0][tid] + red[1][tid]) + (red[2][tid] + red[3][tid]);
  }
}

// 512 threads: chunked parallel reduce of partial[256][128] -> g[128], then
// chunked classifier dot g@Wc[128][64] + bc. Max serial chain: 64 loads.
__global__ __launch_bounds__(512) void k_final(const float* __restrict__ partial,
                                               const float* __restrict__ Wc,
                                               const float* __restrict__ bc,
                                               float* __restrict__ out, int n_nodes) {
  __shared__ float red[4][128];
  __shared__ float gs[128];
  __shared__ float red2[8][64];
  int tid = threadIdx.x;
  int j = tid & 127;
  int c = tid >> 7;  // 4 chunks of 64 partials
  float s = 0.f;
#pragma unroll
  for (int b = 0; b < 64; ++b) s += partial[(size_t)(c * 64 + b) * 128 + j];
  red[c][j] = s;
  __syncthreads();
  if (tid < 128) {
    float g = (red[0][tid] + red[1][tid]) + (red[2][tid] + red[3][tid]);
    gs[tid] = g / (float)n_nodes;
  }
  __syncthreads();
  {
    int jo = tid & 63;
    int c2 = tid >> 6;  // 8 chunks of 16 k
    float s2 = 0.f;
#pragma unroll
    for (int d = 0; d < 16; ++d)
      s2 += gs[c2 * 16 + d] * Wc[(size_t)(c2 * 16 + d) * 64 + jo];
    red2[c2][jo] = s2;
  }
  __syncthreads();
  if (tid < 64) {
    float o = bc[tid];
#pragma unroll
    for (int c2 = 0; c2 < 8; ++c2) o += red2[c2][tid];
    out[tid] = o;
  }
}

extern "C" void kernel_launch(void* const* d_in, const int* in_sizes, int n_in,
                              void* d_out, int out_size, void* d_ws, size_t ws_size,
                              hipStream_t stream) {
  const float* x = (const float*)d_in[0];
  const int* ei = (const int*)d_in[1];
  const float* Ws11 = (const float*)d_in[2];
  const float* Wn11 = (const float*)d_in[3];
  const float* b11 = (const float*)d_in[4];
  const float* Ws12 = (const float*)d_in[5];
  const float* Wn12 = (const float*)d_in[6];
  const float* b12 = (const float*)d_in[7];
  const float* Ws21 = (const float*)d_in[8];
  const float* Wn21 = (const float*)d_in[9];
  const float* b21 = (const float*)d_in[10];
  const float* Ws22 = (const float*)d_in[11];
  const float* Wn22 = (const float*)d_in[12];
  const float* b22 = (const float*)d_in[13];
  const float* Wc = (const float*)d_in[14];
  const float* bc = (const float*)d_in[15];

  int N = in_sizes[0] / 128;
  int E = in_sizes[1] / 2;
  const int* src = ei;
  const int* tgt = ei + E;

  int bdiv = (N + 7) / 8;        // bucket = tgt / bdiv, 0..7
  int cap = E / 8 + 8192;        // per-bucket staging capacity

  // workspace layout (256B-aligned chunks)
  char* w = (char*)d_ws;
  size_t off = 0;
  auto alloc = [&](size_t bytes) {
    void* p = w + off;
    off += (bytes + 255) & ~(size_t)255;
    return p;
  };
  __half* xh = (__half*)alloc((size_t)N * 128 * 2);
  __half* hA = (__half*)alloc((size_t)N * 128 * 2);
  __half* hB = (__half*)alloc((size_t)N * 128 * 2);
  __half* aggb = (__half*)alloc((size_t)N * 128 * 2);
  __half* Wt = (__half*)alloc((size_t)4 * 32768 * 2);
  float* partial = (float*)alloc((size_t)256 * 128 * 4);
  float* inv_deg = (float*)alloc((size_t)N * 4);
  int* deg = (int*)alloc((size_t)N * 4);
  int* row_start = (int*)alloc((size_t)(N + 1) * 4);
  int* cursor = (int*)alloc((size_t)N * 4);
  int* csr_src = (int*)alloc((size_t)E * 4);
  int* scanp = (int*)alloc((size_t)N * 4);
  int* blocksum = (int*)alloc((size_t)256 * 4);
  unsigned long long* staging =
      (unsigned long long*)alloc((size_t)8 * cap * 8);
  int* bucket_fill = (int*)alloc((size_t)8 * 4);

  hipMemsetAsync(deg, 0, (size_t)N * 4, stream);
  hipMemsetAsync(bucket_fill, 0, 8 * 4, stream);
  hipMemsetAsync(partial, 0, (size_t)256 * 128 * 4, stream);

  int nb = (N + 255) / 256;
  int bb = (E + 511) / 512;
  k_bucket<<<bb, 256, 0, stream>>>(src, tgt, deg, staging, bucket_fill, E, bdiv, cap);
  k_scan1<<<nb, 256, 0, stream>>>(deg, scanp, blocksum, inv_deg, N);
  k_scan2<<<1, 256, 0, stream>>>(blocksum, nb);
  k_scan3<<<nb, 256, 0, stream>>>(scanp, blocksum, row_start, cursor, N, E);
  k_scatter2<<<448, 256, 0, stream>>>(staging, bucket_fill, cursor, csr_src, cap);

  int total8 = N * 128 / 8;
  k_cvt_x<<<(total8 + 255) / 256, 256, 0, stream>>>(x, xh, total8);
  WPack wp;
  wp.s[0] = Ws11; wp.s[1] = Ws12; wp.s[2] = Ws21; wp.s[3] = Ws22;
  wp.n[0] = Wn11; wp.n[1] = Wn12; wp.n[2] = Wn21; wp.n[3] = Wn22;
  k_prep_w<<<dim3(128, 4), 256, 0, stream>>>(wp, Wt);

  int ab = (N + 3) / 4;     // k_agg_h: 4 waves/block, 1 node/wave
  int lb = (N + 63) / 64;   // k_linear_mfma: 64 rows/block

  // layer 1: xh -> hA
  k_agg_h<<<ab, 256, 0, stream>>>(xh, csr_src, row_start, inv_deg, aggb, N);
  k_linear_mfma<<<lb, 256, 0, stream>>>(xh, aggb, Wt + 0 * 32768, b11, hA, N);
  // layer 2: hA -> hB
  k_agg_h<<<ab, 256, 0, stream>>>(hA, csr_src, row_start, inv_deg, aggb, N);
  k_linear_mfma<<<lb, 256, 0, stream>>>(hA, aggb, Wt + 1 * 32768, b12, hB, N);
  // layer 3: hB -> hA
  k_agg_h<<<ab, 256, 0, stream>>>(hB, csr_src, row_start, inv_deg, aggb, N);
  k_linear_mfma<<<lb, 256, 0, stream>>>(hB, aggb, Wt + 2 * 32768, b21, hA, N);
  // layer 4: hA -> hB
  k_agg_h<<<ab, 256, 0, stream>>>(hA, csr_src, row_start, inv_deg, aggb, N);
  k_linear_mfma<<<lb, 256, 0, stream>>>(hA, aggb, Wt + 3 * 32768, b22, hB, N);

  k_pool<<<256, 256, 0, stream>>>(hB, partial, N);
  k_final<<<1, 512, 0, stream>>>(partial, Wc, bc, (float*)d_out, N);
}

// Round 14
// 349.378 us; speedup vs baseline: 1.4872x; 1.0248x over previous
//
#include <hip/hip_runtime.h>
#include <hip/hip_bf16.h>
#include <hip/hip_fp16.h>

// GraphSAGE: 4x (mean-agg SAGEConv + ReLU) -> mean pool -> linear classifier
// N=50000, E=800000, dims 128->128->64. fp16 feature storage, fp32 accum,
// MFMA (16x16x32 f16) for the dual linear layers.
// CSR build: bucketed two-phase scatter, 2048 edges/block (round 13: 512
// edges/block REGRESSED 40->50us — per-block overhead beats occupancy; the
// ~25MB random deg-atomic churn is occupancy-insensitive. Round 12: separate
// hist also regressed. Inline deg atomics + 2048 chunk is the measured best.)
// NOTE (rounds 8+12): XCD dim-sliced gathers failed BOTH times — fetch did
// not drop (no L2 residency from blockIdx%8->XCD here). Gather is at the
// 8-XCD x 12.8MB L2-warming floor (~38us/layer). Keep full-row, 1 wave/node.
// NOTE (round 10): linear with 16 rows/wave was B-load-bound -> 64 rows/wave;
// round 14: B-fragments preloaded to registers (Wt L2-hot, 64 VGPRs).

typedef _Float16 f16x8 __attribute__((ext_vector_type(8)));
typedef float f32x4 __attribute__((ext_vector_type(4)));

// --- phase A: deg histogram + bucket (tgt,src) pairs into dense staging.
// Wave-aggregated LDS counters: 8 ballots/wave, 1 leader atomic per bucket
// per wave (vs 64 per-thread atomics -> LDS serialization).
__global__ __launch_bounds__(256) void k_bucket(
    const int* __restrict__ src, const int* __restrict__ tgt,
    int* __restrict__ deg, unsigned long long* __restrict__ staging,
    int* __restrict__ bucket_fill, int E, int bdiv, int cap) {
  __shared__ unsigned long long buf[8][320];
  __shared__ int cnt[8];
  __shared__ int base[8];
  int tid = threadIdx.x;
  int lane = tid & 63;
  if (tid < 8) cnt[tid] = 0;
  __syncthreads();
  int e0 = blockIdx.x * 2048;
#pragma unroll
  for (int i = 0; i < 8; ++i) {
    int e = e0 + i * 256 + tid;
    int b = -1;
    unsigned long long pair = 0;
    if (e < E) {
      int t = tgt[e];
      int s = src[e];
      atomicAdd(&deg[t], 1);
      b = t / bdiv;
      pair = ((unsigned long long)(unsigned)t << 32) | (unsigned)s;
    }
#pragma unroll
    for (int bk = 0; bk < 8; ++bk) {
      bool mine = (b == bk);
      unsigned long long mask = __ballot(mine);
      if (mask == 0ull) continue;  // ballot is wave-uniform
      int cw = __popcll(mask);
      int leader = __ffsll((unsigned long long)mask) - 1;
      int p0 = 0;
      if (lane == leader) p0 = atomicAdd(&cnt[bk], cw);
      p0 = __shfl(p0, leader, 64);
      if (mine) {
        int p = p0 + __popcll(mask & ((1ull << lane) - 1ull));
        if (p < 320) {
          buf[bk][p] = pair;
        } else {  // rare overflow: reserve a global slot directly
          int gp = atomicAdd(&bucket_fill[bk], 1);
          staging[(size_t)bk * cap + gp] = pair;
        }
      }
    }
  }
  __syncthreads();
  if (tid < 8) {
    int c = min(cnt[tid], 320);
    base[tid] = atomicAdd(&bucket_fill[tid], c);
    cnt[tid] = c;
  }
  __syncthreads();
  for (int b = 0; b < 8; ++b) {
    int c = cnt[b];
    for (int p = tid; p < c; p += 256)
      staging[(size_t)b * cap + base[b] + p] = buf[b][p];
  }
}

// --- phase B: per-bucket scatter; block g -> bucket g&7 (bucket-local writes) ---
__global__ __launch_bounds__(256) void k_scatter2(
    const unsigned long long* __restrict__ staging,
    const int* __restrict__ bucket_fill, int* __restrict__ cursor,
    int* __restrict__ csr_src, int cap) {
  int b = blockIdx.x & 7;
  int nchunk = gridDim.x >> 3;
  int chunk = blockIdx.x >> 3;
  int n = bucket_fill[b];
  const unsigned long long* sb = staging + (size_t)b * cap;
  for (int i0 = chunk * 2048; i0 < n; i0 += nchunk * 2048) {
#pragma unroll
    for (int t = 0; t < 8; ++t) {
      int i = i0 + t * 256 + (int)threadIdx.x;
      if (i < n) {
        unsigned long long pair = sb[i];
        int tg = (int)(pair >> 32);
        int s = (int)(pair & 0xffffffffu);
        int pos = atomicAdd(&cursor[tg], 1);
        csr_src[pos] = s;
      }
    }
  }
}

// --- parallel exclusive scan over deg[0..n) -> row_start, cursor, inv_deg ---
__global__ __launch_bounds__(256) void k_scan1(const int* __restrict__ deg,
                                               int* __restrict__ partial,
                                               int* __restrict__ blocksum,
                                               float* __restrict__ inv_deg, int n) {
  __shared__ int s[256];
  int tid = threadIdx.x;
  int i = blockIdx.x * 256 + tid;
  int v = (i < n) ? deg[i] : 0;
  s[tid] = v;
  __syncthreads();
  for (int off = 1; off < 256; off <<= 1) {
    int t = (tid >= off) ? s[tid - off] : 0;
    __syncthreads();
    s[tid] += t;
    __syncthreads();
  }
  if (i < n) {
    partial[i] = s[tid] - v;
    inv_deg[i] = 1.0f / fmaxf((float)v, 1.0f);
  }
  if (tid == 255) blocksum[blockIdx.x] = s[255];
}

__global__ __launch_bounds__(256) void k_scan2(int* __restrict__ blocksum, int nb) {
  __shared__ int s[256];
  int tid = threadIdx.x;
  int v = (tid < nb) ? blocksum[tid] : 0;
  s[tid] = v;
  __syncthreads();
  for (int off = 1; off < 256; off <<= 1) {
    int t = (tid >= off) ? s[tid - off] : 0;
    __syncthreads();
    s[tid] += t;
    __syncthreads();
  }
  if (tid < nb) blocksum[tid] = s[tid] - v;
}

__global__ __launch_bounds__(256) void k_scan3(const int* __restrict__ partial,
                                               const int* __restrict__ blocksum,
                                               int* __restrict__ row_start,
                                               int* __restrict__ cursor, int n, int E) {
  int i = blockIdx.x * 256 + threadIdx.x;
  if (i < n) {
    int r = partial[i] + blocksum[blockIdx.x];
    row_start[i] = r;
    cursor[i] = r;
  }
  if (i == 0) row_start[n] = E;
}

// x fp32 -> fp16, 8 elements/thread
__global__ __launch_bounds__(256) void k_cvt_x(const float* __restrict__ x,
                                               __half* __restrict__ xh, int total8) {
  int i = blockIdx.x * 256 + threadIdx.x;
  if (i >= total8) return;
  const float4* p = (const float4*)(x + (size_t)i * 8);
  float4 v0 = p[0], v1 = p[1];
  f16x8 o;
  o[0] = (_Float16)v0.x; o[1] = (_Float16)v0.y; o[2] = (_Float16)v0.z; o[3] = (_Float16)v0.w;
  o[4] = (_Float16)v1.x; o[5] = (_Float16)v1.y; o[6] = (_Float16)v1.z; o[7] = (_Float16)v1.w;
  *(f16x8*)(xh + (size_t)i * 8) = o;
}

struct WPack {
  const float* s[4];
  const float* n[4];
};

// Wt[layer][n][k] (k in [0,256): k<128 -> Ws[k][n], else Wn[k-128][n]), fp16
__global__ __launch_bounds__(256) void k_prep_w(WPack p, __half* __restrict__ Wt) {
  int l = blockIdx.y;
  int i = blockIdx.x * 256 + threadIdx.x;  // [0, 32768)
  int n = i >> 8;
  int k = i & 255;
  const float* W = (k < 128) ? p.s[l] : p.n[l];
  float v = W[(size_t)(k & 127) * 128 + n];
  Wt[(size_t)l * 32768 + (size_t)n * 256 + k] = __float2half(v);
}

// One wave per node. q=lane>>4 selects edge-in-group-of-4; lane&15 selects 8
// dims (f16x8 = 16B/lane -> one 256B row per 16-lane group). Main loop covers
// 16 edges -> 8 row loads in flight per lane; tails of 8/4/1.
// Fold q-groups with shfl_xor(16,32); fp32 accumulation throughout.
__global__ __launch_bounds__(256) void k_agg_h(
    const __half* __restrict__ h, const int* __restrict__ csr_src,
    const int* __restrict__ row_start, const float* __restrict__ inv_deg,
    __half* __restrict__ agg, int n_nodes) {
  int gw = (blockIdx.x * 256 + (int)threadIdx.x) >> 6;
  int lane = threadIdx.x & 63;
  if (gw >= n_nodes) return;
  int q = lane >> 4;         // edge slot 0..3
  int dl = (lane & 15) * 8;  // dims dl..dl+7
  int beg = row_start[gw];
  int end = row_start[gw + 1];
  float a0 = 0.f, a1 = 0.f, a2 = 0.f, a3 = 0.f;
  float a4 = 0.f, a5 = 0.f, a6 = 0.f, a7 = 0.f;
  int e = beg;
  for (; e + 16 <= end; e += 16) {
    int i0 = csr_src[e + q];
    int i1 = csr_src[e + 4 + q];
    int i2 = csr_src[e + 8 + q];
    int i3 = csr_src[e + 12 + q];
    f16x8 v0 = *(const f16x8*)(h + (size_t)i0 * 128 + dl);
    f16x8 v1 = *(const f16x8*)(h + (size_t)i1 * 128 + dl);
    f16x8 v2 = *(const f16x8*)(h + (size_t)i2 * 128 + dl);
    f16x8 v3 = *(const f16x8*)(h + (size_t)i3 * 128 + dl);
    a0 += ((float)v0[0] + (float)v1[0]) + ((float)v2[0] + (float)v3[0]);
    a1 += ((float)v0[1] + (float)v1[1]) + ((float)v2[1] + (float)v3[1]);
    a2 += ((float)v0[2] + (float)v1[2]) + ((float)v2[2] + (float)v3[2]);
    a3 += ((float)v0[3] + (float)v1[3]) + ((float)v2[3] + (float)v3[3]);
    a4 += ((float)v0[4] + (float)v1[4]) + ((float)v2[4] + (float)v3[4]);
    a5 += ((float)v0[5] + (float)v1[5]) + ((float)v2[5] + (float)v3[5]);
    a6 += ((float)v0[6] + (float)v1[6]) + ((float)v2[6] + (float)v3[6]);
    a7 += ((float)v0[7] + (float)v1[7]) + ((float)v2[7] + (float)v3[7]);
  }
  for (; e + 8 <= end; e += 8) {
    int i0 = csr_src[e + q];
    int i1 = csr_src[e + 4 + q];
    f16x8 v0 = *(const f16x8*)(h + (size_t)i0 * 128 + dl);
    f16x8 v1 = *(const f16x8*)(h + (size_t)i1 * 128 + dl);
    a0 += (float)v0[0] + (float)v1[0];
    a1 += (float)v0[1] + (float)v1[1];
    a2 += (float)v0[2] + (float)v1[2];
    a3 += (float)v0[3] + (float)v1[3];
    a4 += (float)v0[4] + (float)v1[4];
    a5 += (float)v0[5] + (float)v1[5];
    a6 += (float)v0[6] + (float)v1[6];
    a7 += (float)v0[7] + (float)v1[7];
  }
  for (; e + 4 <= end; e += 4) {
    int i0 = csr_src[e + q];
    f16x8 v0 = *(const f16x8*)(h + (size_t)i0 * 128 + dl);
    a0 += (float)v0[0];
    a1 += (float)v0[1];
    a2 += (float)v0[2];
    a3 += (float)v0[3];
    a4 += (float)v0[4];
    a5 += (float)v0[5];
    a6 += (float)v0[6];
    a7 += (float)v0[7];
  }
  if (e + q < end) {
    int i0 = csr_src[e + q];
    f16x8 v0 = *(const f16x8*)(h + (size_t)i0 * 128 + dl);
    a0 += (float)v0[0];
    a1 += (float)v0[1];
    a2 += (float)v0[2];
    a3 += (float)v0[3];
    a4 += (float)v0[4];
    a5 += (float)v0[5];
    a6 += (float)v0[6];
    a7 += (float)v0[7];
  }
  // fold the 4 edge slots (16-lane groups hold identical dim ranges)
  a0 += __shfl_xor(a0, 16, 64);
  a1 += __shfl_xor(a1, 16, 64);
  a2 += __shfl_xor(a2, 16, 64);
  a3 += __shfl_xor(a3, 16, 64);
  a4 += __shfl_xor(a4, 16, 64);
  a5 += __shfl_xor(a5, 16, 64);
  a6 += __shfl_xor(a6, 16, 64);
  a7 += __shfl_xor(a7, 16, 64);
  a0 += __shfl_xor(a0, 32, 64);
  a1 += __shfl_xor(a1, 32, 64);
  a2 += __shfl_xor(a2, 32, 64);
  a3 += __shfl_xor(a3, 32, 64);
  a4 += __shfl_xor(a4, 32, 64);
  a5 += __shfl_xor(a5, 32, 64);
  a6 += __shfl_xor(a6, 32, 64);
  a7 += __shfl_xor(a7, 32, 64);
  if (q == 0) {
    float wgt = inv_deg[gw];
    f16x8 r;
    r[0] = (_Float16)(a0 * wgt);
    r[1] = (_Float16)(a1 * wgt);
    r[2] = (_Float16)(a2 * wgt);
    r[3] = (_Float16)(a3 * wgt);
    r[4] = (_Float16)(a4 * wgt);
    r[5] = (_Float16)(a5 * wgt);
    r[6] = (_Float16)(a6 * wgt);
    r[7] = (_Float16)(a7 * wgt);
    *(f16x8*)(agg + (size_t)gw * 128 + dl) = r;
  }
}

// out[m][n] = relu( h[m]@Ws + agg[m]@Wn + b ), K=256 via mfma_f32_16x16x32_f16.
// Block = 256 threads = 4 waves, 64 rows. Wave w owns col-quarter cq=w (32
// cols) and ALL 64 rows (4 row-tiles). All 16 B-fragments preloaded into
// registers before the MFMA loop (Wt is L2-hot; removes B-load latency from
// the inner-loop critical path).
__global__ __launch_bounds__(256) void k_linear_mfma(
    const __half* __restrict__ h, const __half* __restrict__ agg,
    const __half* __restrict__ Wt, const float* __restrict__ bias,
    __half* __restrict__ out, int n_nodes) {
  int tid = threadIdx.x;
  int cq = tid >> 6;  // wave -> col quarter
  int lane = tid & 63;
  int node0 = blockIdx.x * 64;
  int lr = lane & 15;
  int lg = lane >> 4;

  // preload all B fragments: bs[ks][ct]
  f16x8 bs[8][2];
#pragma unroll
  for (int ks = 0; ks < 8; ++ks) {
    int kb = ks * 32 + lg * 8;
    bs[ks][0] = *(const f16x8*)(Wt + (size_t)(cq * 32 + lr) * 256 + kb);
    bs[ks][1] = *(const f16x8*)(Wt + (size_t)(cq * 32 + 16 + lr) * 256 + kb);
  }

  f32x4 acc[4][2];
#pragma unroll
  for (int rt = 0; rt < 4; ++rt)
#pragma unroll
    for (int ct = 0; ct < 2; ++ct) acc[rt][ct] = (f32x4){0.f, 0.f, 0.f, 0.f};

  const __half* hrow[4];
  const __half* grow[4];
#pragma unroll
  for (int rt = 0; rt < 4; ++rt) {
    int arow = node0 + rt * 16 + lr;
    if (arow >= n_nodes) arow = n_nodes - 1;
    hrow[rt] = h + (size_t)arow * 128;
    grow[rt] = agg + (size_t)arow * 128;
  }

#pragma unroll
  for (int ks = 0; ks < 8; ++ks) {
    int koff = (ks & 3) * 32 + lg * 8;
#pragma unroll
    for (int rt = 0; rt < 4; ++rt) {
      f16x8 a = (ks < 4) ? *(const f16x8*)(hrow[rt] + koff)
                         : *(const f16x8*)(grow[rt] + koff);
      acc[rt][0] = __builtin_amdgcn_mfma_f32_16x16x32_f16(a, bs[ks][0], acc[rt][0], 0, 0, 0);
      acc[rt][1] = __builtin_amdgcn_mfma_f32_16x16x32_f16(a, bs[ks][1], acc[rt][1], 0, 0, 0);
    }
  }

#pragma unroll
  for (int ct = 0; ct < 2; ++ct) {
    int n_col = cq * 32 + ct * 16 + lr;
    float bv = bias[n_col];
#pragma unroll
    for (int rt = 0; rt < 4; ++rt) {
#pragma unroll
      for (int r = 0; r < 4; ++r) {
        int m = node0 + rt * 16 + lg * 4 + r;
        if (m < n_nodes)
          out[(size_t)m * 128 + n_col] = __float2half(fmaxf(acc[rt][ct][r] + bv, 0.f));
      }
    }
  }
}

// 256 blocks x 256 threads; wave w handles rows blk*4+w (stride 1024), lane owns
// 2 dims via half2; LDS reduce across the 4 waves -> partial[blk][128].
__global__ __launch_bounds__(256) void k_pool(const __half* __restrict__ h,
                                              float* __restrict__ partial, int n_nodes) {
  __shared__ float red[4][128];
  int tid = threadIdx.x;
  int lane = tid & 63;
  int w = tid >> 6;
  float a0 = 0.f, a1 = 0.f;
  for (int n = blockIdx.x * 4 + w; n < n_nodes; n += gridDim.x * 4) {
    float2 f = __half22float2(*(const __half2*)(h + (size_t)n * 128 + lane * 2));
    a0 += f.x;
    a1 += f.y;
  }
  red[w][lane * 2] = a0;
  red[w][lane * 2 + 1] = a1;
  __syncthreads();
  if (tid < 128) {
    partial[(size_t)blockIdx.x * 128 + tid] =
        (red[0][tid] + red[1][tid]) + (red[2][tid] + red[3][tid]);
  }
}

// 512 threads: chunked parallel reduce of partial[256][128] -> g[128], then
// chunked classifier dot g@Wc[128][64] + bc. Max serial chain: 64 loads.
__global__ __launch_bounds__(512) void k_final(const float* __restrict__ partial,
                                               const float* __restrict__ Wc,
                                               const float* __restrict__ bc,
                                               float* __restrict__ out, int n_nodes) {
  __shared__ float red[4][128];
  __shared__ float gs[128];
  __shared__ float red2[8][64];
  int tid = threadIdx.x;
  int j = tid & 127;
  int c = tid >> 7;  // 4 chunks of 64 partials
  float s = 0.f;
#pragma unroll
  for (int b = 0; b < 64; ++b) s += partial[(size_t)(c * 64 + b) * 128 + j];
  red[c][j] = s;
  __syncthreads();
  if (tid < 128) {
    float g = (red[0][tid] + red[1][tid]) + (red[2][tid] + red[3][tid]);
    gs[tid] = g / (float)n_nodes;
  }
  __syncthreads();
  {
    int jo = tid & 63;
    int c2 = tid >> 6;  // 8 chunks of 16 k
    float s2 = 0.f;
#pragma unroll
    for (int d = 0; d < 16; ++d)
      s2 += gs[c2 * 16 + d] * Wc[(size_t)(c2 * 16 + d) * 64 + jo];
    red2[c2][jo] = s2;
  }
  __syncthreads();
  if (tid < 64) {
    float o = bc[tid];
#pragma unroll
    for (int c2 = 0; c2 < 8; ++c2) o += red2[c2][tid];
    out[tid] = o;
  }
}

extern "C" void kernel_launch(void* const* d_in, const int* in_sizes, int n_in,
                              void* d_out, int out_size, void* d_ws, size_t ws_size,
                              hipStream_t stream) {
  const float* x = (const float*)d_in[0];
  const int* ei = (const int*)d_in[1];
  const float* Ws11 = (const float*)d_in[2];
  const float* Wn11 = (const float*)d_in[3];
  const float* b11 = (const float*)d_in[4];
  const float* Ws12 = (const float*)d_in[5];
  const float* Wn12 = (const float*)d_in[6];
  const float* b12 = (const float*)d_in[7];
  const float* Ws21 = (const float*)d_in[8];
  const float* Wn21 = (const float*)d_in[9];
  const float* b21 = (const float*)d_in[10];
  const float* Ws22 = (const float*)d_in[11];
  const float* Wn22 = (const float*)d_in[12];
  const float* b22 = (const float*)d_in[13];
  const float* Wc = (const float*)d_in[14];
  const float* bc = (const float*)d_in[15];

  int N = in_sizes[0] / 128;
  int E = in_sizes[1] / 2;
  const int* src = ei;
  const int* tgt = ei + E;

  int bdiv = (N + 7) / 8;        // bucket = tgt / bdiv, 0..7
  int cap = E / 8 + 8192;        // per-bucket staging capacity

  // workspace layout (256B-aligned chunks)
  char* w = (char*)d_ws;
  size_t off = 0;
  auto alloc = [&](size_t bytes) {
    void* p = w + off;
    off += (bytes + 255) & ~(size_t)255;
    return p;
  };
  __half* xh = (__half*)alloc((size_t)N * 128 * 2);
  __half* hA = (__half*)alloc((size_t)N * 128 * 2);
  __half* hB = (__half*)alloc((size_t)N * 128 * 2);
  __half* aggb = (__half*)alloc((size_t)N * 128 * 2);
  __half* Wt = (__half*)alloc((size_t)4 * 32768 * 2);
  float* partial = (float*)alloc((size_t)256 * 128 * 4);
  float* inv_deg = (float*)alloc((size_t)N * 4);
  int* deg = (int*)alloc((size_t)N * 4);
  int* row_start = (int*)alloc((size_t)(N + 1) * 4);
  int* cursor = (int*)alloc((size_t)N * 4);
  int* csr_src = (int*)alloc((size_t)E * 4);
  int* scanp = (int*)alloc((size_t)N * 4);
  int* blocksum = (int*)alloc((size_t)256 * 4);
  unsigned long long* staging =
      (unsigned long long*)alloc((size_t)8 * cap * 8);
  int* bucket_fill = (int*)alloc((size_t)8 * 4);

  hipMemsetAsync(deg, 0, (size_t)N * 4, stream);
  hipMemsetAsync(bucket_fill, 0, 8 * 4, stream);
  hipMemsetAsync(partial, 0, (size_t)256 * 128 * 4, stream);

  int nb = (N + 255) / 256;
  int bb = (E + 2047) / 2048;
  k_bucket<<<bb, 256, 0, stream>>>(src, tgt, deg, staging, bucket_fill, E, bdiv, cap);
  k_scan1<<<nb, 256, 0, stream>>>(deg, scanp, blocksum, inv_deg, N);
  k_scan2<<<1, 256, 0, stream>>>(blocksum, nb);
  k_scan3<<<nb, 256, 0, stream>>>(scanp, blocksum, row_start, cursor, N, E);
  k_scatter2<<<448, 256, 0, stream>>>(staging, bucket_fill, cursor, csr_src, cap);

  int total8 = N * 128 / 8;
  k_cvt_x<<<(total8 + 255) / 256, 256, 0, stream>>>(x, xh, total8);
  WPack wp;
  wp.s[0] = Ws11; wp.s[1] = Ws12; wp.s[2] = Ws21; wp.s[3] = Ws22;
  wp.n[0] = Wn11; wp.n[1] = Wn12; wp.n[2] = Wn21; wp.n[3] = Wn22;
  k_prep_w<<<dim3(128, 4), 256, 0, stream>>>(wp, Wt);

  int ab = (N + 3) / 4;     // k_agg_h: 4 waves/block, 1 node/wave
  int lb = (N + 63) / 64;   // k_linear_mfma: 64 rows/block

  // layer 1: xh -> hA
  k_agg_h<<<ab, 256, 0, stream>>>(xh, csr_src, row_start, inv_deg, aggb, N);
  k_linear_mfma<<<lb, 256, 0, stream>>>(xh, aggb, Wt + 0 * 32768, b11, hA, N);
  // layer 2: hA -> hB
  k_agg_h<<<ab, 256, 0, stream>>>(hA, csr_src, row_start, inv_deg, aggb, N);
  k_linear_mfma<<<lb, 256, 0, stream>>>(hA, aggb, Wt + 1 * 32768, b12, hB, N);
  // layer 3: hB -> hA
  k_agg_h<<<ab, 256, 0, stream>>>(hB, csr_src, row_start, inv_deg, aggb, N);
  k_linear_mfma<<<lb, 256, 0, stream>>>(hB, aggb, Wt + 2 * 32768, b21, hA, N);
  // layer 4: hA -> hB
  k_agg_h<<<ab, 256, 0, stream>>>(hA, csr_src, row_start, inv_deg, aggb, N);
  k_linear_mfma<<<lb, 256, 0, stream>>>(hA, aggb, Wt + 3 * 32768, b22, hB, N);

  k_pool<<<256, 256, 0, stream>>>(hB, partial, N);
  k_final<<<1, 512, 0, stream>>>(partial, Wc, bc, (float*)d_out, N);
}

// Round 15
// 344.358 us; speedup vs baseline: 1.5088x; 1.0146x over previous
//
#include <hip/hip_runtime.h>
#include <hip/hip_bf16.h>
#include <hip/hip_fp16.h>
#include <hip/hip_fp8.h>

// GraphSAGE: 4x (mean-agg SAGEConv + ReLU) -> mean pool -> linear classifier
// N=50000, E=800000, dims 128->128->64.
// h kept in fp16 (linear/MFMA path) + fp8 e4m3 shadow copy (gather path):
// the gather is L2-miss-traffic-bound (~85MB/layer @ ~2.4TB/s), so halving
// row bytes (256B->128B) is the remaining lever. Self path + MFMA stay fp16.
// fp8 decode = bit-trick (expman<<7, x256 folded into 1/deg), fp16 accum.
// CSR build: bucketed two-phase scatter, 2048 edges/block, inline deg atomics
// (rounds 12/13: separate hist and small chunks both regressed).
// NOTE (rounds 8+12): XCD dim-sliced gathers failed twice (no L2 residency
// from blockIdx%8->XCD). NOTE (round 10): 64 rows/wave in linear (B amortize).

typedef _Float16 f16x8 __attribute__((ext_vector_type(8)));
typedef float f32x4 __attribute__((ext_vector_type(4)));

// --- phase A: deg histogram + bucket (tgt,src) pairs into dense staging ---
__global__ __launch_bounds__(256) void k_bucket(
    const int* __restrict__ src, const int* __restrict__ tgt,
    int* __restrict__ deg, unsigned long long* __restrict__ staging,
    int* __restrict__ bucket_fill, int E, int bdiv, int cap) {
  __shared__ unsigned long long buf[8][320];
  __shared__ int cnt[8];
  __shared__ int base[8];
  int tid = threadIdx.x;
  int lane = tid & 63;
  if (tid < 8) cnt[tid] = 0;
  __syncthreads();
  int e0 = blockIdx.x * 2048;
#pragma unroll
  for (int i = 0; i < 8; ++i) {
    int e = e0 + i * 256 + tid;
    int b = -1;
    unsigned long long pair = 0;
    if (e < E) {
      int t = tgt[e];
      int s = src[e];
      atomicAdd(&deg[t], 1);
      b = t / bdiv;
      pair = ((unsigned long long)(unsigned)t << 32) | (unsigned)s;
    }
#pragma unroll
    for (int bk = 0; bk < 8; ++bk) {
      bool mine = (b == bk);
      unsigned long long mask = __ballot(mine);
      if (mask == 0ull) continue;  // ballot is wave-uniform
      int cw = __popcll(mask);
      int leader = __ffsll((unsigned long long)mask) - 1;
      int p0 = 0;
      if (lane == leader) p0 = atomicAdd(&cnt[bk], cw);
      p0 = __shfl(p0, leader, 64);
      if (mine) {
        int p = p0 + __popcll(mask & ((1ull << lane) - 1ull));
        if (p < 320) {
          buf[bk][p] = pair;
        } else {  // rare overflow: reserve a global slot directly
          int gp = atomicAdd(&bucket_fill[bk], 1);
          staging[(size_t)bk * cap + gp] = pair;
        }
      }
    }
  }
  __syncthreads();
  if (tid < 8) {
    int c = min(cnt[tid], 320);
    base[tid] = atomicAdd(&bucket_fill[tid], c);
    cnt[tid] = c;
  }
  __syncthreads();
  for (int b = 0; b < 8; ++b) {
    int c = cnt[b];
    for (int p = tid; p < c; p += 256)
      staging[(size_t)b * cap + base[b] + p] = buf[b][p];
  }
}

// --- phase B: per-bucket scatter; block g -> bucket g&7 (bucket-local writes) ---
__global__ __launch_bounds__(256) void k_scatter2(
    const unsigned long long* __restrict__ staging,
    const int* __restrict__ bucket_fill, int* __restrict__ cursor,
    int* __restrict__ csr_src, int cap) {
  int b = blockIdx.x & 7;
  int nchunk = gridDim.x >> 3;
  int chunk = blockIdx.x >> 3;
  int n = bucket_fill[b];
  const unsigned long long* sb = staging + (size_t)b * cap;
  for (int i0 = chunk * 2048; i0 < n; i0 += nchunk * 2048) {
#pragma unroll
    for (int t = 0; t < 8; ++t) {
      int i = i0 + t * 256 + (int)threadIdx.x;
      if (i < n) {
        unsigned long long pair = sb[i];
        int tg = (int)(pair >> 32);
        int s = (int)(pair & 0xffffffffu);
        int pos = atomicAdd(&cursor[tg], 1);
        csr_src[pos] = s;
      }
    }
  }
}

// --- parallel exclusive scan over deg[0..n) -> row_start, cursor, inv_deg ---
__global__ __launch_bounds__(256) void k_scan1(const int* __restrict__ deg,
                                               int* __restrict__ partial,
                                               int* __restrict__ blocksum,
                                               float* __restrict__ inv_deg, int n) {
  __shared__ int s[256];
  int tid = threadIdx.x;
  int i = blockIdx.x * 256 + tid;
  int v = (i < n) ? deg[i] : 0;
  s[tid] = v;
  __syncthreads();
  for (int off = 1; off < 256; off <<= 1) {
    int t = (tid >= off) ? s[tid - off] : 0;
    __syncthreads();
    s[tid] += t;
    __syncthreads();
  }
  if (i < n) {
    partial[i] = s[tid] - v;
    inv_deg[i] = 1.0f / fmaxf((float)v, 1.0f);
  }
  if (tid == 255) blocksum[blockIdx.x] = s[255];
}

__global__ __launch_bounds__(256) void k_scan2(int* __restrict__ blocksum, int nb) {
  __shared__ int s[256];
  int tid = threadIdx.x;
  int v = (tid < nb) ? blocksum[tid] : 0;
  s[tid] = v;
  __syncthreads();
  for (int off = 1; off < 256; off <<= 1) {
    int t = (tid >= off) ? s[tid - off] : 0;
    __syncthreads();
    s[tid] += t;
    __syncthreads();
  }
  if (tid < nb) blocksum[tid] = s[tid] - v;
}

__global__ __launch_bounds__(256) void k_scan3(const int* __restrict__ partial,
                                               const int* __restrict__ blocksum,
                                               int* __restrict__ row_start,
                                               int* __restrict__ cursor, int n, int E) {
  int i = blockIdx.x * 256 + threadIdx.x;
  if (i < n) {
    int r = partial[i] + blocksum[blockIdx.x];
    row_start[i] = r;
    cursor[i] = r;
  }
  if (i == 0) row_start[n] = E;
}

// x fp32 -> fp16 + fp8 shadow, 8 elements/thread
__global__ __launch_bounds__(256) void k_cvt_x(const float* __restrict__ x,
                                               __half* __restrict__ xh,
                                               unsigned char* __restrict__ xh8,
                                               int total8) {
  int i = blockIdx.x * 256 + threadIdx.x;
  if (i >= total8) return;
  const float4* p = (const float4*)(x + (size_t)i * 8);
  float4 v0 = p[0], v1 = p[1];
  float f[8] = {v0.x, v0.y, v0.z, v0.w, v1.x, v1.y, v1.z, v1.w};
  f16x8 o;
  unsigned long long u8 = 0;
#pragma unroll
  for (int j = 0; j < 8; ++j) {
    o[j] = (_Float16)f[j];
    __hip_fp8_e4m3 q(f[j]);
    u8 |= (unsigned long long)(*reinterpret_cast<unsigned char*>(&q)) << (8 * j);
  }
  *(f16x8*)(xh + (size_t)i * 8) = o;
  *(unsigned long long*)(xh8 + (size_t)i * 8) = u8;
}

// fp16 -> fp8 shadow copy (streamed; ~3us)
__global__ __launch_bounds__(256) void k_h8(const __half* __restrict__ h,
                                            unsigned char* __restrict__ h8,
                                            int total8) {
  int i = blockIdx.x * 256 + threadIdx.x;
  if (i >= total8) return;
  f16x8 v = *(const f16x8*)(h + (size_t)i * 8);
  unsigned long long u8 = 0;
#pragma unroll
  for (int j = 0; j < 8; ++j) {
    __hip_fp8_e4m3 q((float)v[j]);
    u8 |= (unsigned long long)(*reinterpret_cast<unsigned char*>(&q)) << (8 * j);
  }
  *(unsigned long long*)(h8 + (size_t)i * 8) = u8;
}

struct WPack {
  const float* s[4];
  const float* n[4];
};

// Wt[layer][n][k] (k in [0,256): k<128 -> Ws[k][n], else Wn[k-128][n]), fp16
__global__ __launch_bounds__(256) void k_prep_w(WPack p, __half* __restrict__ Wt) {
  int l = blockIdx.y;
  int i = blockIdx.x * 256 + threadIdx.x;  // [0, 32768)
  int n = i >> 8;
  int k = i & 255;
  const float* W = (k < 128) ? p.s[l] : p.n[l];
  float v = W[(size_t)(k & 127) * 128 + n];
  Wt[(size_t)l * 32768 + (size_t)n * 256 + k] = __float2half(v);
}

// fp8 gather. One wave per node; q=lane>>4 edge slot (4), lane&15 -> 8 dims
// (uint2 = 8B -> one 128B row per 16-lane group). fp8->fp16 decode bit-trick:
// h16bits = sign<<8 | expman<<7, true value = that x 256 (bias 15 vs 7);
// x256 folded into the final 1/deg scale. fp16 (__half2) accumulation
// (values <= ~0.8 after the implicit /256). Fold slots via shfl+hadd2.
__global__ __launch_bounds__(256) void k_agg8(
    const unsigned char* __restrict__ h8, const int* __restrict__ csr_src,
    const int* __restrict__ row_start, const float* __restrict__ inv_deg,
    __half* __restrict__ agg, int n_nodes) {
  int gw = (blockIdx.x * 256 + (int)threadIdx.x) >> 6;
  int lane = threadIdx.x & 63;
  if (gw >= n_nodes) return;
  int q = lane >> 4;          // edge slot 0..3
  int dl = (lane & 15) * 8;   // dims/bytes dl..dl+7
  int beg = row_start[gw];
  int end = row_start[gw + 1];
  __half2 ac0 = __float2half2_rn(0.f), ac1 = ac0, ac2 = ac0, ac3 = ac0;

  auto accum = [&](uint2 w) {
    unsigned v0 = w.x, v1 = w.y;
    unsigned e0 = ((v0 & 0x00800080u) << 8) | ((v0 & 0x007f007fu) << 7);
    unsigned o0 = (((v0 >> 8) & 0x00800080u) << 8) | (((v0 >> 8) & 0x007f007fu) << 7);
    unsigned e1 = ((v1 & 0x00800080u) << 8) | ((v1 & 0x007f007fu) << 7);
    unsigned o1 = (((v1 >> 8) & 0x00800080u) << 8) | (((v1 >> 8) & 0x007f007fu) << 7);
    ac0 = __hadd2(ac0, *reinterpret_cast<__half2*>(&e0));
    ac1 = __hadd2(ac1, *reinterpret_cast<__half2*>(&o0));
    ac2 = __hadd2(ac2, *reinterpret_cast<__half2*>(&e1));
    ac3 = __hadd2(ac3, *reinterpret_cast<__half2*>(&o1));
  };

  int e = beg;
  for (; e + 16 <= end; e += 16) {
    int i0 = csr_src[e + q];
    int i1 = csr_src[e + 4 + q];
    int i2 = csr_src[e + 8 + q];
    int i3 = csr_src[e + 12 + q];
    uint2 w0 = *(const uint2*)(h8 + (size_t)i0 * 128 + dl);
    uint2 w1 = *(const uint2*)(h8 + (size_t)i1 * 128 + dl);
    uint2 w2 = *(const uint2*)(h8 + (size_t)i2 * 128 + dl);
    uint2 w3 = *(const uint2*)(h8 + (size_t)i3 * 128 + dl);
    accum(w0);
    accum(w1);
    accum(w2);
    accum(w3);
  }
  for (; e + 8 <= end; e += 8) {
    int i0 = csr_src[e + q];
    int i1 = csr_src[e + 4 + q];
    uint2 w0 = *(const uint2*)(h8 + (size_t)i0 * 128 + dl);
    uint2 w1 = *(const uint2*)(h8 + (size_t)i1 * 128 + dl);
    accum(w0);
    accum(w1);
  }
  for (; e + 4 <= end; e += 4) {
    int i0 = csr_src[e + q];
    accum(*(const uint2*)(h8 + (size_t)i0 * 128 + dl));
  }
  if (e + q < end) {
    int i0 = csr_src[e + q];
    accum(*(const uint2*)(h8 + (size_t)i0 * 128 + dl));
  }
  // fold the 4 edge slots (16-lane groups hold identical dim ranges)
#pragma unroll
  for (int off = 16; off <= 32; off <<= 1) {
    int t0 = __shfl_xor(*reinterpret_cast<int*>(&ac0), off, 64);
    int t1 = __shfl_xor(*reinterpret_cast<int*>(&ac1), off, 64);
    int t2 = __shfl_xor(*reinterpret_cast<int*>(&ac2), off, 64);
    int t3 = __shfl_xor(*reinterpret_cast<int*>(&ac3), off, 64);
    ac0 = __hadd2(ac0, *reinterpret_cast<__half2*>(&t0));
    ac1 = __hadd2(ac1, *reinterpret_cast<__half2*>(&t1));
    ac2 = __hadd2(ac2, *reinterpret_cast<__half2*>(&t2));
    ac3 = __hadd2(ac3, *reinterpret_cast<__half2*>(&t3));
  }
  if (q == 0) {
    float wgt = inv_deg[gw] * 256.0f;  // x256 undoes the fp8 decode bias shift
    float2 f0 = __half22float2(ac0);   // dims (dl+0, dl+2)
    float2 f1 = __half22float2(ac1);   // dims (dl+1, dl+3)
    float2 f2 = __half22float2(ac2);   // dims (dl+4, dl+6)
    float2 f3 = __half22float2(ac3);   // dims (dl+5, dl+7)
    f16x8 r;
    r[0] = (_Float16)(f0.x * wgt);
    r[1] = (_Float16)(f1.x * wgt);
    r[2] = (_Float16)(f0.y * wgt);
    r[3] = (_Float16)(f1.y * wgt);
    r[4] = (_Float16)(f2.x * wgt);
    r[5] = (_Float16)(f3.x * wgt);
    r[6] = (_Float16)(f2.y * wgt);
    r[7] = (_Float16)(f3.y * wgt);
    *(f16x8*)(agg + (size_t)gw * 128 + dl) = r;
  }
}

// out[m][n] = relu( h[m]@Ws + agg[m]@Wn + b ), K=256 via mfma_f32_16x16x32_f16.
// Block = 256 threads = 4 waves, 64 rows. Wave w owns col-quarter cq=w (32
// cols) and ALL 64 rows; 16 B-fragments preloaded to registers (Wt L2-hot).
__global__ __launch_bounds__(256) void k_linear_mfma(
    const __half* __restrict__ h, const __half* __restrict__ agg,
    const __half* __restrict__ Wt, const float* __restrict__ bias,
    __half* __restrict__ out, int n_nodes) {
  int tid = threadIdx.x;
  int cq = tid >> 6;  // wave -> col quarter
  int lane = tid & 63;
  int node0 = blockIdx.x * 64;
  int lr = lane & 15;
  int lg = lane >> 4;

  f16x8 bs[8][2];
#pragma unroll
  for (int ks = 0; ks < 8; ++ks) {
    int kb = ks * 32 + lg * 8;
    bs[ks][0] = *(const f16x8*)(Wt + (size_t)(cq * 32 + lr) * 256 + kb);
    bs[ks][1] = *(const f16x8*)(Wt + (size_t)(cq * 32 + 16 + lr) * 256 + kb);
  }

  f32x4 acc[4][2];
#pragma unroll
  for (int rt = 0; rt < 4; ++rt)
#pragma unroll
    for (int ct = 0; ct < 2; ++ct) acc[rt][ct] = (f32x4){0.f, 0.f, 0.f, 0.f};

  const __half* hrow[4];
  const __half* grow[4];
#pragma unroll
  for (int rt = 0; rt < 4; ++rt) {
    int arow = node0 + rt * 16 + lr;
    if (arow >= n_nodes) arow = n_nodes - 1;
    hrow[rt] = h + (size_t)arow * 128;
    grow[rt] = agg + (size_t)arow * 128;
  }

#pragma unroll
  for (int ks = 0; ks < 8; ++ks) {
    int koff = (ks & 3) * 32 + lg * 8;
#pragma unroll
    for (int rt = 0; rt < 4; ++rt) {
      f16x8 a = (ks < 4) ? *(const f16x8*)(hrow[rt] + koff)
                         : *(const f16x8*)(grow[rt] + koff);
      acc[rt][0] = __builtin_amdgcn_mfma_f32_16x16x32_f16(a, bs[ks][0], acc[rt][0], 0, 0, 0);
      acc[rt][1] = __builtin_amdgcn_mfma_f32_16x16x32_f16(a, bs[ks][1], acc[rt][1], 0, 0, 0);
    }
  }

#pragma unroll
  for (int ct = 0; ct < 2; ++ct) {
    int n_col = cq * 32 + ct * 16 + lr;
    float bv = bias[n_col];
#pragma unroll
    for (int rt = 0; rt < 4; ++rt) {
#pragma unroll
      for (int r = 0; r < 4; ++r) {
        int m = node0 + rt * 16 + lg * 4 + r;
        if (m < n_nodes)
          out[(size_t)m * 128 + n_col] = __float2half(fmaxf(acc[rt][ct][r] + bv, 0.f));
      }
    }
  }
}

// 256 blocks x 256 threads; wave w handles rows blk*4+w (stride 1024), lane owns
// 2 dims via half2; LDS reduce across the 4 waves -> partial[blk][128].
__global__ __launch_bounds__(256) void k_pool(const __half* __restrict__ h,
                                              float* __restrict__ partial, int n_nodes) {
  __shared__ float red[4][128];
  int tid = threadIdx.x;
  int lane = tid & 63;
  int w = tid >> 6;
  float a0 = 0.f, a1 = 0.f;
  for (int n = blockIdx.x * 4 + w; n < n_nodes; n += gridDim.x * 4) {
    float2 f = __half22float2(*(const __half2*)(h + (size_t)n * 128 + lane * 2));
    a0 += f.x;
    a1 += f.y;
  }
  red[w][lane * 2] = a0;
  red[w][lane * 2 + 1] = a1;
  __syncthreads();
  if (tid < 128) {
    partial[(size_t)blockIdx.x * 128 + tid] =
        (red[0][tid] + red[1][tid]) + (red[2][tid] + red[3][tid]);
  }
}

// 512 threads: chunked parallel reduce of partial[256][128] -> g[128], then
// chunked classifier dot g@Wc[128][64] + bc. Max serial chain: 64 loads.
__global__ __launch_bounds__(512) void k_final(const float* __restrict__ partial,
                                               const float* __restrict__ Wc,
                                               const float* __restrict__ bc,
                                               float* __restrict__ out, int n_nodes) {
  __shared__ float red[4][128];
  __shared__ float gs[128];
  __shared__ float red2[8][64];
  int tid = threadIdx.x;
  int j = tid & 127;
  int c = tid >> 7;  // 4 chunks of 64 partials
  float s = 0.f;
#pragma unroll
  for (int b = 0; b < 64; ++b) s += partial[(size_t)(c * 64 + b) * 128 + j];
  red[c][j] = s;
  __syncthreads();
  if (tid < 128) {
    float g = (red[0][tid] + red[1][tid]) + (red[2][tid] + red[3][tid]);
    gs[tid] = g / (float)n_nodes;
  }
  __syncthreads();
  {
    int jo = tid & 63;
    int c2 = tid >> 6;  // 8 chunks of 16 k
    float s2 = 0.f;
#pragma unroll
    for (int d = 0; d < 16; ++d)
      s2 += gs[c2 * 16 + d] * Wc[(size_t)(c2 * 16 + d) * 64 + jo];
    red2[c2][jo] = s2;
  }
  __syncthreads();
  if (tid < 64) {
    float o = bc[tid];
#pragma unroll
    for (int c2 = 0; c2 < 8; ++c2) o += red2[c2][tid];
    out[tid] = o;
  }
}

extern "C" void kernel_launch(void* const* d_in, const int* in_sizes, int n_in,
                              void* d_out, int out_size, void* d_ws, size_t ws_size,
                              hipStream_t stream) {
  const float* x = (const float*)d_in[0];
  const int* ei = (const int*)d_in[1];
  const float* Ws11 = (const float*)d_in[2];
  const float* Wn11 = (const float*)d_in[3];
  const float* b11 = (const float*)d_in[4];
  const float* Ws12 = (const float*)d_in[5];
  const float* Wn12 = (const float*)d_in[6];
  const float* b12 = (const float*)d_in[7];
  const float* Ws21 = (const float*)d_in[8];
  const float* Wn21 = (const float*)d_in[9];
  const float* b21 = (const float*)d_in[10];
  const float* Ws22 = (const float*)d_in[11];
  const float* Wn22 = (const float*)d_in[12];
  const float* b22 = (const float*)d_in[13];
  const float* Wc = (const float*)d_in[14];
  const float* bc = (const float*)d_in[15];

  int N = in_sizes[0] / 128;
  int E = in_sizes[1] / 2;
  const int* src = ei;
  const int* tgt = ei + E;

  int bdiv = (N + 7) / 8;        // bucket = tgt / bdiv, 0..7
  int cap = E / 8 + 8192;        // per-bucket staging capacity

  // workspace layout (256B-aligned chunks)
  char* w = (char*)d_ws;
  size_t off = 0;
  auto alloc = [&](size_t bytes) {
    void* p = w + off;
    off += (bytes + 255) & ~(size_t)255;
    return p;
  };
  __half* xh = (__half*)alloc((size_t)N * 128 * 2);
  __half* hA = (__half*)alloc((size_t)N * 128 * 2);
  __half* hB = (__half*)alloc((size_t)N * 128 * 2);
  __half* aggb = (__half*)alloc((size_t)N * 128 * 2);
  unsigned char* xh8 = (unsigned char*)alloc((size_t)N * 128);
  unsigned char* h8A = (unsigned char*)alloc((size_t)N * 128);
  unsigned char* h8B = (unsigned char*)alloc((size_t)N * 128);
  __half* Wt = (__half*)alloc((size_t)4 * 32768 * 2);
  float* partial = (float*)alloc((size_t)256 * 128 * 4);
  float* inv_deg = (float*)alloc((size_t)N * 4);
  int* deg = (int*)alloc((size_t)N * 4);
  int* row_start = (int*)alloc((size_t)(N + 1) * 4);
  int* cursor = (int*)alloc((size_t)N * 4);
  int* csr_src = (int*)alloc((size_t)E * 4);
  int* scanp = (int*)alloc((size_t)N * 4);
  int* blocksum = (int*)alloc((size_t)256 * 4);
  unsigned long long* staging =
      (unsigned long long*)alloc((size_t)8 * cap * 8);
  int* bucket_fill = (int*)alloc((size_t)8 * 4);

  hipMemsetAsync(deg, 0, (size_t)N * 4, stream);
  hipMemsetAsync(bucket_fill, 0, 8 * 4, stream);
  hipMemsetAsync(partial, 0, (size_t)256 * 128 * 4, stream);

  int nb = (N + 255) / 256;
  int bb = (E + 2047) / 2048;
  k_bucket<<<bb, 256, 0, stream>>>(src, tgt, deg, staging, bucket_fill, E, bdiv, cap);
  k_scan1<<<nb, 256, 0, stream>>>(deg, scanp, blocksum, inv_deg, N);
  k_scan2<<<1, 256, 0, stream>>>(blocksum, nb);
  k_scan3<<<nb, 256, 0, stream>>>(scanp, blocksum, row_start, cursor, N, E);
  k_scatter2<<<448, 256, 0, stream>>>(staging, bucket_fill, cursor, csr_src, cap);

  int total8 = N * 128 / 8;
  int cb = (total8 + 255) / 256;
  k_cvt_x<<<cb, 256, 0, stream>>>(x, xh, xh8, total8);
  WPack wp;
  wp.s[0] = Ws11; wp.s[1] = Ws12; wp.s[2] = Ws21; wp.s[3] = Ws22;
  wp.n[0] = Wn11; wp.n[1] = Wn12; wp.n[2] = Wn21; wp.n[3] = Wn22;
  k_prep_w<<<dim3(128, 4), 256, 0, stream>>>(wp, Wt);

  int ab = (N + 3) / 4;     // k_agg8: 4 waves/block, 1 node/wave
  int lb = (N + 63) / 64;   // k_linear_mfma: 64 rows/block

  // layer 1: xh -> hA
  k_agg8<<<ab, 256, 0, stream>>>(xh8, csr_src, row_start, inv_deg, aggb, N);
  k_linear_mfma<<<lb, 256, 0, stream>>>(xh, aggb, Wt + 0 * 32768, b11, hA, N);
  k_h8<<<cb, 256, 0, stream>>>(hA, h8A, total8);
  // layer 2: hA -> hB
  k_agg8<<<ab, 256, 0, stream>>>(h8A, csr_src, row_start, inv_deg, aggb, N);
  k_linear_mfma<<<lb, 256, 0, stream>>>(hA, aggb, Wt + 1 * 32768, b12, hB, N);
  k_h8<<<cb, 256, 0, stream>>>(hB, h8B, total8);
  // layer 3: hB -> hA
  k_agg8<<<ab, 256, 0, stream>>>(h8B, csr_src, row_start, inv_deg, aggb, N);
  k_linear_mfma<<<lb, 256, 0, stream>>>(hB, aggb, Wt + 2 * 32768, b21, hA, N);
  k_h8<<<cb, 256, 0, stream>>>(hA, h8A, total8);
  // layer 4: hA -> hB
  k_agg8<<<ab, 256, 0, stream>>>(h8A, csr_src, row_start, inv_deg, aggb, N);
  k_linear_mfma<<<lb, 256, 0, stream>>>(hA, aggb, Wt + 3 * 32768, b22, hB, N);

  k_pool<<<256, 256, 0, stream>>>(hB, partial, N);
  k_final<<<1, 512, 0, stream>>>(partial, Wc, bc, (float*)d_out, N);
}

// Round 16
// 334.676 us; speedup vs baseline: 1.5525x; 1.0289x over previous
//
#include <hip/hip_runtime.h>
#include <hip/hip_bf16.h>
#include <hip/hip_fp16.h>
#include <hip/hip_fp8.h>

// GraphSAGE: 4x (mean-agg SAGEConv + ReLU) -> mean pool -> linear classifier
// N=50000, E=800000, dims 128->128->64.
// h in fp16 (MFMA path) + fp8 e4m3 shadow (gather path, produced in the
// linear epilogue). Gather is latency/request-bound after fp8 (round 15).
// deg histogram uses per-XCD replicas: 800k random atomics on ONE 200KB array
// ping-pong lines across 8 non-coherent L2s (25MB writeback churn measured);
// 8 replicas keep each copy XCD-local, written back once (~1.6MB).
// CSR build: bucketed two-phase scatter, 2048 edges/block (rounds 12/13:
// separate hist and small chunks both regressed).
// NOTE (rounds 8+12): XCD dim-sliced gathers failed twice (no L2 residency
// from blockIdx%8->XCD on reads). NOTE (round 10): 64 rows/wave in linear.

typedef _Float16 f16x8 __attribute__((ext_vector_type(8)));
typedef float f32x4 __attribute__((ext_vector_type(4)));

// --- phase A: deg histogram (per-XCD replicas) + bucket (tgt,src) pairs ---
__global__ __launch_bounds__(256) void k_bucket(
    const int* __restrict__ src, const int* __restrict__ tgt,
    int* __restrict__ deg8, unsigned long long* __restrict__ staging,
    int* __restrict__ bucket_fill, int E, int bdiv, int cap, int N) {
  __shared__ unsigned long long buf[8][320];
  __shared__ int cnt[8];
  __shared__ int base[8];
  int tid = threadIdx.x;
  int lane = tid & 63;
  if (tid < 8) cnt[tid] = 0;
  __syncthreads();
  int* degrep = deg8 + (size_t)(blockIdx.x & 7) * N;  // XCD-local replica
  int e0 = blockIdx.x * 2048;
#pragma unroll
  for (int i = 0; i < 8; ++i) {
    int e = e0 + i * 256 + tid;
    int b = -1;
    unsigned long long pair = 0;
    if (e < E) {
      int t = tgt[e];
      int s = src[e];
      atomicAdd(&degrep[t], 1);
      b = t / bdiv;
      pair = ((unsigned long long)(unsigned)t << 32) | (unsigned)s;
    }
#pragma unroll
    for (int bk = 0; bk < 8; ++bk) {
      bool mine = (b == bk);
      unsigned long long mask = __ballot(mine);
      if (mask == 0ull) continue;  // ballot is wave-uniform
      int cw = __popcll(mask);
      int leader = __ffsll((unsigned long long)mask) - 1;
      int p0 = 0;
      if (lane == leader) p0 = atomicAdd(&cnt[bk], cw);
      p0 = __shfl(p0, leader, 64);
      if (mine) {
        int p = p0 + __popcll(mask & ((1ull << lane) - 1ull));
        if (p < 320) {
          buf[bk][p] = pair;
        } else {  // rare overflow: reserve a global slot directly
          int gp = atomicAdd(&bucket_fill[bk], 1);
          staging[(size_t)bk * cap + gp] = pair;
        }
      }
    }
  }
  __syncthreads();
  if (tid < 8) {
    int c = min(cnt[tid], 320);
    base[tid] = atomicAdd(&bucket_fill[tid], c);
    cnt[tid] = c;
  }
  __syncthreads();
  for (int b = 0; b < 8; ++b) {
    int c = cnt[b];
    for (int p = tid; p < c; p += 256)
      staging[(size_t)b * cap + base[b] + p] = buf[b][p];
  }
}

// --- phase B: per-bucket scatter; block g -> bucket g&7 (bucket-local writes) ---
__global__ __launch_bounds__(256) void k_scatter2(
    const unsigned long long* __restrict__ staging,
    const int* __restrict__ bucket_fill, int* __restrict__ cursor,
    int* __restrict__ csr_src, int cap) {
  int b = blockIdx.x & 7;
  int nchunk = gridDim.x >> 3;
  int chunk = blockIdx.x >> 3;
  int n = bucket_fill[b];
  const unsigned long long* sb = staging + (size_t)b * cap;
  for (int i0 = chunk * 2048; i0 < n; i0 += nchunk * 2048) {
#pragma unroll
    for (int t = 0; t < 8; ++t) {
      int i = i0 + t * 256 + (int)threadIdx.x;
      if (i < n) {
        unsigned long long pair = sb[i];
        int tg = (int)(pair >> 32);
        int s = (int)(pair & 0xffffffffu);
        int pos = atomicAdd(&cursor[tg], 1);
        csr_src[pos] = s;
      }
    }
  }
}

// --- parallel exclusive scan; deg = sum of 8 XCD replicas ---
__global__ __launch_bounds__(256) void k_scan1(const int* __restrict__ deg8,
                                               int* __restrict__ partial,
                                               int* __restrict__ blocksum,
                                               float* __restrict__ inv_deg,
                                               int n) {
  __shared__ int s[256];
  int tid = threadIdx.x;
  int i = blockIdx.x * 256 + tid;
  int v = 0;
  if (i < n) {
#pragma unroll
    for (int k = 0; k < 8; ++k) v += deg8[(size_t)k * n + i];
  }
  s[tid] = v;
  __syncthreads();
  for (int off = 1; off < 256; off <<= 1) {
    int t = (tid >= off) ? s[tid - off] : 0;
    __syncthreads();
    s[tid] += t;
    __syncthreads();
  }
  if (i < n) {
    partial[i] = s[tid] - v;
    inv_deg[i] = 1.0f / fmaxf((float)v, 1.0f);
  }
  if (tid == 255) blocksum[blockIdx.x] = s[255];
}

__global__ __launch_bounds__(256) void k_scan2(int* __restrict__ blocksum, int nb) {
  __shared__ int s[256];
  int tid = threadIdx.x;
  int v = (tid < nb) ? blocksum[tid] : 0;
  s[tid] = v;
  __syncthreads();
  for (int off = 1; off < 256; off <<= 1) {
    int t = (tid >= off) ? s[tid - off] : 0;
    __syncthreads();
    s[tid] += t;
    __syncthreads();
  }
  if (tid < nb) blocksum[tid] = s[tid] - v;
}

__global__ __launch_bounds__(256) void k_scan3(const int* __restrict__ partial,
                                               const int* __restrict__ blocksum,
                                               int* __restrict__ row_start,
                                               int* __restrict__ cursor, int n, int E) {
  int i = blockIdx.x * 256 + threadIdx.x;
  if (i < n) {
    int r = partial[i] + blocksum[blockIdx.x];
    row_start[i] = r;
    cursor[i] = r;
  }
  if (i == 0) row_start[n] = E;
}

// x fp32 -> fp16 + fp8 shadow, 8 elements/thread
__global__ __launch_bounds__(256) void k_cvt_x(const float* __restrict__ x,
                                               __half* __restrict__ xh,
                                               unsigned char* __restrict__ xh8,
                                               int total8) {
  int i = blockIdx.x * 256 + threadIdx.x;
  if (i >= total8) return;
  const float4* p = (const float4*)(x + (size_t)i * 8);
  float4 v0 = p[0], v1 = p[1];
  float f[8] = {v0.x, v0.y, v0.z, v0.w, v1.x, v1.y, v1.z, v1.w};
  f16x8 o;
  unsigned long long u8 = 0;
#pragma unroll
  for (int j = 0; j < 8; ++j) {
    o[j] = (_Float16)f[j];
    __hip_fp8_e4m3 q(f[j]);
    u8 |= (unsigned long long)(*reinterpret_cast<unsigned char*>(&q)) << (8 * j);
  }
  *(f16x8*)(xh + (size_t)i * 8) = o;
  *(unsigned long long*)(xh8 + (size_t)i * 8) = u8;
}

struct WPack {
  const float* s[4];
  const float* n[4];
};

// Wt[layer][n][k] (k in [0,256): k<128 -> Ws[k][n], else Wn[k-128][n]), fp16
__global__ __launch_bounds__(256) void k_prep_w(WPack p, __half* __restrict__ Wt) {
  int l = blockIdx.y;
  int i = blockIdx.x * 256 + threadIdx.x;  // [0, 32768)
  int n = i >> 8;
  int k = i & 255;
  const float* W = (k < 128) ? p.s[l] : p.n[l];
  float v = W[(size_t)(k & 127) * 128 + n];
  Wt[(size_t)l * 32768 + (size_t)n * 256 + k] = __float2half(v);
}

// fp8 gather. One wave per node; q=lane>>4 edge slot (4), lane&15 -> 8 dims
// (uint2 = 8B -> one 128B row per 16-lane group). fp8->fp16 decode bit-trick:
// h16bits = sign<<8 | expman<<7, true value = that x 256 (bias 15 vs 7);
// x256 folded into the final 1/deg scale. fp16 (__half2) accumulation.
__global__ __launch_bounds__(256) void k_agg8(
    const unsigned char* __restrict__ h8, const int* __restrict__ csr_src,
    const int* __restrict__ row_start, const float* __restrict__ inv_deg,
    __half* __restrict__ agg, int n_nodes) {
  int gw = (blockIdx.x * 256 + (int)threadIdx.x) >> 6;
  int lane = threadIdx.x & 63;
  if (gw >= n_nodes) return;
  int q = lane >> 4;          // edge slot 0..3
  int dl = (lane & 15) * 8;   // dims/bytes dl..dl+7
  int beg = row_start[gw];
  int end = row_start[gw + 1];
  __half2 ac0 = __float2half2_rn(0.f), ac1 = ac0, ac2 = ac0, ac3 = ac0;

  auto accum = [&](uint2 w) {
    unsigned v0 = w.x, v1 = w.y;
    unsigned e0 = ((v0 & 0x00800080u) << 8) | ((v0 & 0x007f007fu) << 7);
    unsigned o0 = (((v0 >> 8) & 0x00800080u) << 8) | (((v0 >> 8) & 0x007f007fu) << 7);
    unsigned e1 = ((v1 & 0x00800080u) << 8) | ((v1 & 0x007f007fu) << 7);
    unsigned o1 = (((v1 >> 8) & 0x00800080u) << 8) | (((v1 >> 8) & 0x007f007fu) << 7);
    ac0 = __hadd2(ac0, *reinterpret_cast<__half2*>(&e0));
    ac1 = __hadd2(ac1, *reinterpret_cast<__half2*>(&o0));
    ac2 = __hadd2(ac2, *reinterpret_cast<__half2*>(&e1));
    ac3 = __hadd2(ac3, *reinterpret_cast<__half2*>(&o1));
  };

  int e = beg;
  for (; e + 16 <= end; e += 16) {
    int i0 = csr_src[e + q];
    int i1 = csr_src[e + 4 + q];
    int i2 = csr_src[e + 8 + q];
    int i3 = csr_src[e + 12 + q];
    uint2 w0 = *(const uint2*)(h8 + (size_t)i0 * 128 + dl);
    uint2 w1 = *(const uint2*)(h8 + (size_t)i1 * 128 + dl);
    uint2 w2 = *(const uint2*)(h8 + (size_t)i2 * 128 + dl);
    uint2 w3 = *(const uint2*)(h8 + (size_t)i3 * 128 + dl);
    accum(w0);
    accum(w1);
    accum(w2);
    accum(w3);
  }
  for (; e + 8 <= end; e += 8) {
    int i0 = csr_src[e + q];
    int i1 = csr_src[e + 4 + q];
    uint2 w0 = *(const uint2*)(h8 + (size_t)i0 * 128 + dl);
    uint2 w1 = *(const uint2*)(h8 + (size_t)i1 * 128 + dl);
    accum(w0);
    accum(w1);
  }
  for (; e + 4 <= end; e += 4) {
    int i0 = csr_src[e + q];
    accum(*(const uint2*)(h8 + (size_t)i0 * 128 + dl));
  }
  if (e + q < end) {
    int i0 = csr_src[e + q];
    accum(*(const uint2*)(h8 + (size_t)i0 * 128 + dl));
  }
  // fold the 4 edge slots (16-lane groups hold identical dim ranges)
#pragma unroll
  for (int off = 16; off <= 32; off <<= 1) {
    int t0 = __shfl_xor(*reinterpret_cast<int*>(&ac0), off, 64);
    int t1 = __shfl_xor(*reinterpret_cast<int*>(&ac1), off, 64);
    int t2 = __shfl_xor(*reinterpret_cast<int*>(&ac2), off, 64);
    int t3 = __shfl_xor(*reinterpret_cast<int*>(&ac3), off, 64);
    ac0 = __hadd2(ac0, *reinterpret_cast<__half2*>(&t0));
    ac1 = __hadd2(ac1, *reinterpret_cast<__half2*>(&t1));
    ac2 = __hadd2(ac2, *reinterpret_cast<__half2*>(&t2));
    ac3 = __hadd2(ac3, *reinterpret_cast<__half2*>(&t3));
  }
  if (q == 0) {
    float wgt = inv_deg[gw] * 256.0f;  // x256 undoes the fp8 decode bias shift
    float2 f0 = __half22float2(ac0);   // dims (dl+0, dl+2)
    float2 f1 = __half22float2(ac1);   // dims (dl+1, dl+3)
    float2 f2 = __half22float2(ac2);   // dims (dl+4, dl+6)
    float2 f3 = __half22float2(ac3);   // dims (dl+5, dl+7)
    f16x8 r;
    r[0] = (_Float16)(f0.x * wgt);
    r[1] = (_Float16)(f1.x * wgt);
    r[2] = (_Float16)(f0.y * wgt);
    r[3] = (_Float16)(f1.y * wgt);
    r[4] = (_Float16)(f2.x * wgt);
    r[5] = (_Float16)(f3.x * wgt);
    r[6] = (_Float16)(f2.y * wgt);
    r[7] = (_Float16)(f3.y * wgt);
    *(f16x8*)(agg + (size_t)gw * 128 + dl) = r;
  }
}

// out[m][n] = relu( h[m]@Ws + agg[m]@Wn + b ), K=256 via mfma_f32_16x16x32_f16.
// Block = 256 threads = 4 waves, 64 rows. Wave w owns col-quarter cq=w (32
// cols) and ALL 64 rows; 16 B-fragments preloaded to registers (Wt L2-hot).
// Epilogue also emits the fp8 e4m3 shadow copy (out8, nullable) — replaces
// the separate k_h8 re-read kernel.
__global__ __launch_bounds__(256) void k_linear_mfma(
    const __half* __restrict__ h, const __half* __restrict__ agg,
    const __half* __restrict__ Wt, const float* __restrict__ bias,
    __half* __restrict__ out, unsigned char* __restrict__ out8, int n_nodes) {
  int tid = threadIdx.x;
  int cq = tid >> 6;  // wave -> col quarter
  int lane = tid & 63;
  int node0 = blockIdx.x * 64;
  int lr = lane & 15;
  int lg = lane >> 4;

  f16x8 bs[8][2];
#pragma unroll
  for (int ks = 0; ks < 8; ++ks) {
    int kb = ks * 32 + lg * 8;
    bs[ks][0] = *(const f16x8*)(Wt + (size_t)(cq * 32 + lr) * 256 + kb);
    bs[ks][1] = *(const f16x8*)(Wt + (size_t)(cq * 32 + 16 + lr) * 256 + kb);
  }

  f32x4 acc[4][2];
#pragma unroll
  for (int rt = 0; rt < 4; ++rt)
#pragma unroll
    for (int ct = 0; ct < 2; ++ct) acc[rt][ct] = (f32x4){0.f, 0.f, 0.f, 0.f};

  const __half* hrow[4];
  const __half* grow[4];
#pragma unroll
  for (int rt = 0; rt < 4; ++rt) {
    int arow = node0 + rt * 16 + lr;
    if (arow >= n_nodes) arow = n_nodes - 1;
    hrow[rt] = h + (size_t)arow * 128;
    grow[rt] = agg + (size_t)arow * 128;
  }

#pragma unroll
  for (int ks = 0; ks < 8; ++ks) {
    int koff = (ks & 3) * 32 + lg * 8;
#pragma unroll
    for (int rt = 0; rt < 4; ++rt) {
      f16x8 a = (ks < 4) ? *(const f16x8*)(hrow[rt] + koff)
                         : *(const f16x8*)(grow[rt] + koff);
      acc[rt][0] = __builtin_amdgcn_mfma_f32_16x16x32_f16(a, bs[ks][0], acc[rt][0], 0, 0, 0);
      acc[rt][1] = __builtin_amdgcn_mfma_f32_16x16x32_f16(a, bs[ks][1], acc[rt][1], 0, 0, 0);
    }
  }

#pragma unroll
  for (int ct = 0; ct < 2; ++ct) {
    int n_col = cq * 32 + ct * 16 + lr;
    float bv = bias[n_col];
#pragma unroll
    for (int rt = 0; rt < 4; ++rt) {
#pragma unroll
      for (int r = 0; r < 4; ++r) {
        int m = node0 + rt * 16 + lg * 4 + r;
        if (m < n_nodes) {
          float v = fmaxf(acc[rt][ct][r] + bv, 0.f);
          out[(size_t)m * 128 + n_col] = __float2half(v);
          if (out8) {
            __hip_fp8_e4m3 q(v);
            out8[(size_t)m * 128 + n_col] = *reinterpret_cast<unsigned char*>(&q);
          }
        }
      }
    }
  }
}

// 256 blocks x 256 threads; wave w handles rows blk*4+w (stride 1024), lane owns
// 2 dims via half2; LDS reduce across the 4 waves -> partial[blk][128].
__global__ __launch_bounds__(256) void k_pool(const __half* __restrict__ h,
                                              float* __restrict__ partial, int n_nodes) {
  __shared__ float red[4][128];
  int tid = threadIdx.x;
  int lane = tid & 63;
  int w = tid >> 6;
  float a0 = 0.f, a1 = 0.f;
  for (int n = blockIdx.x * 4 + w; n < n_nodes; n += gridDim.x * 4) {
    float2 f = __half22float2(*(const __half2*)(h + (size_t)n * 128 + lane * 2));
    a0 += f.x;
    a1 += f.y;
  }
  red[w][lane * 2] = a0;
  red[w][lane * 2 + 1] = a1;
  __syncthreads();
  if (tid < 128) {
    partial[(size_t)blockIdx.x * 128 + tid] =
        (red[0][tid] + red[1][tid]) + (red[2][tid] + red[3][tid]);
  }
}

// 512 threads: chunked parallel reduce of partial[256][128] -> g[128], then
// chunked classifier dot g@Wc[128][64] + bc. Max serial chain: 64 loads.
__global__ __launch_bounds__(512) void k_final(const float* __restrict__ partial,
                                               const float* __restrict__ Wc,
                                               const float* __restrict__ bc,
                                               float* __restrict__ out, int n_nodes) {
  __shared__ float red[4][128];
  __shared__ float gs[128];
  __shared__ float red2[8][64];
  int tid = threadIdx.x;
  int j = tid & 127;
  int c = tid >> 7;  // 4 chunks of 64 partials
  float s = 0.f;
#pragma unroll
  for (int b = 0; b < 64; ++b) s += partial[(size_t)(c * 64 + b) * 128 + j];
  red[c][j] = s;
  __syncthreads();
  if (tid < 128) {
    float g = (red[0][tid] + red[1][tid]) + (red[2][tid] + red[3][tid]);
    gs[tid] = g / (float)n_nodes;
  }
  __syncthreads();
  {
    int jo = tid & 63;
    int c2 = tid >> 6;  // 8 chunks of 16 k
    float s2 = 0.f;
#pragma unroll
    for (int d = 0; d < 16; ++d)
      s2 += gs[c2 * 16 + d] * Wc[(size_t)(c2 * 16 + d) * 64 + jo];
    red2[c2][jo] = s2;
  }
  __syncthreads();
  if (tid < 64) {
    float o = bc[tid];
#pragma unroll
    for (int c2 = 0; c2 < 8; ++c2) o += red2[c2][tid];
    out[tid] = o;
  }
}

extern "C" void kernel_launch(void* const* d_in, const int* in_sizes, int n_in,
                              void* d_out, int out_size, void* d_ws, size_t ws_size,
                              hipStream_t stream) {
  const float* x = (const float*)d_in[0];
  const int* ei = (const int*)d_in[1];
  const float* Ws11 = (const float*)d_in[2];
  const float* Wn11 = (const float*)d_in[3];
  const float* b11 = (const float*)d_in[4];
  const float* Ws12 = (const float*)d_in[5];
  const float* Wn12 = (const float*)d_in[6];
  const float* b12 = (const float*)d_in[7];
  const float* Ws21 = (const float*)d_in[8];
  const float* Wn21 = (const float*)d_in[9];
  const float* b21 = (const float*)d_in[10];
  const float* Ws22 = (const float*)d_in[11];
  const float* Wn22 = (const float*)d_in[12];
  const float* b22 = (const float*)d_in[13];
  const float* Wc = (const float*)d_in[14];
  const float* bc = (const float*)d_in[15];

  int N = in_sizes[0] / 128;
  int E = in_sizes[1] / 2;
  const int* src = ei;
  const int* tgt = ei + E;

  int bdiv = (N + 7) / 8;        // bucket = tgt / bdiv, 0..7
  int cap = E / 8 + 8192;        // per-bucket staging capacity

  // workspace layout (256B-aligned chunks)
  char* w = (char*)d_ws;
  size_t off = 0;
  auto alloc = [&](size_t bytes) {
    void* p = w + off;
    off += (bytes + 255) & ~(size_t)255;
    return p;
  };
  __half* xh = (__half*)alloc((size_t)N * 128 * 2);
  __half* hA = (__half*)alloc((size_t)N * 128 * 2);
  __half* hB = (__half*)alloc((size_t)N * 128 * 2);
  __half* aggb = (__half*)alloc((size_t)N * 128 * 2);
  unsigned char* xh8 = (unsigned char*)alloc((size_t)N * 128);
  unsigned char* h8A = (unsigned char*)alloc((size_t)N * 128);
  unsigned char* h8B = (unsigned char*)alloc((size_t)N * 128);
  __half* Wt = (__half*)alloc((size_t)4 * 32768 * 2);
  float* partial = (float*)alloc((size_t)256 * 128 * 4);
  float* inv_deg = (float*)alloc((size_t)N * 4);
  int* deg8 = (int*)alloc((size_t)8 * N * 4);   // per-XCD replicas
  int* row_start = (int*)alloc((size_t)(N + 1) * 4);
  int* cursor = (int*)alloc((size_t)N * 4);
  int* csr_src = (int*)alloc((size_t)E * 4);
  int* scanp = (int*)alloc((size_t)N * 4);
  int* blocksum = (int*)alloc((size_t)256 * 4);
  unsigned long long* staging =
      (unsigned long long*)alloc((size_t)8 * cap * 8);
  int* bucket_fill = (int*)alloc((size_t)8 * 4);

  hipMemsetAsync(deg8, 0, (size_t)8 * N * 4, stream);
  hipMemsetAsync(bucket_fill, 0, 8 * 4, stream);
  hipMemsetAsync(partial, 0, (size_t)256 * 128 * 4, stream);

  int nb = (N + 255) / 256;
  int bb = (E + 2047) / 2048;
  k_bucket<<<bb, 256, 0, stream>>>(src, tgt, deg8, staging, bucket_fill, E, bdiv, cap, N);
  k_scan1<<<nb, 256, 0, stream>>>(deg8, scanp, blocksum, inv_deg, N);
  k_scan2<<<1, 256, 0, stream>>>(blocksum, nb);
  k_scan3<<<nb, 256, 0, stream>>>(scanp, blocksum, row_start, cursor, N, E);
  k_scatter2<<<448, 256, 0, stream>>>(staging, bucket_fill, cursor, csr_src, cap);

  int total8 = N * 128 / 8;
  int cb = (total8 + 255) / 256;
  k_cvt_x<<<cb, 256, 0, stream>>>(x, xh, xh8, total8);
  WPack wp;
  wp.s[0] = Ws11; wp.s[1] = Ws12; wp.s[2] = Ws21; wp.s[3] = Ws22;
  wp.n[0] = Wn11; wp.n[1] = Wn12; wp.n[2] = Wn21; wp.n[3] = Wn22;
  k_prep_w<<<dim3(128, 4), 256, 0, stream>>>(wp, Wt);

  int ab = (N + 3) / 4;     // k_agg8: 4 waves/block, 1 node/wave
  int lb = (N + 63) / 64;   // k_linear_mfma: 64 rows/block

  // layer 1: xh -> hA (+h8A)
  k_agg8<<<ab, 256, 0, stream>>>(xh8, csr_src, row_start, inv_deg, aggb, N);
  k_linear_mfma<<<lb, 256, 0, stream>>>(xh, aggb, Wt + 0 * 32768, b11, hA, h8A, N);
  // layer 2: hA -> hB (+h8B)
  k_agg8<<<ab, 256, 0, stream>>>(h8A, csr_src, row_start, inv_deg, aggb, N);
  k_linear_mfma<<<lb, 256, 0, stream>>>(hA, aggb, Wt + 1 * 32768, b12, hB, h8B, N);
  // layer 3: hB -> hA (+h8A)
  k_agg8<<<ab, 256, 0, stream>>>(h8B, csr_src, row_start, inv_deg, aggb, N);
  k_linear_mfma<<<lb, 256, 0, stream>>>(hB, aggb, Wt + 2 * 32768, b21, hA, h8A, N);
  // layer 4: hA -> hB (no fp8 needed)
  k_agg8<<<ab, 256, 0, stream>>>(h8A, csr_src, row_start, inv_deg, aggb, N);
  k_linear_mfma<<<lb, 256, 0, stream>>>(hA, aggb, Wt + 3 * 32768, b22, hB, (unsigned char*)nullptr, N);

  k_pool<<<256, 256, 0, stream>>>(hB, partial, N);
  k_final<<<1, 512, 0, stream>>>(partial, Wc, bc, (float*)d_out, N);
}

// Round 17
// 332.978 us; speedup vs baseline: 1.5604x; 1.0051x over previous
//
#include <hip/hip_runtime.h>
#include <hip/hip_bf16.h>
#include <hip/hip_fp16.h>
#include <hip/hip_fp8.h>

// GraphSAGE: 4x (mean-agg SAGEConv + ReLU) -> mean pool -> linear classifier
// N=50000, E=800000, dims 128->128->64.
// h in fp16 (MFMA path) + fp8 e4m3 shadow (gather path, produced in the
// linear epilogue). Gather is latency/request-bound after fp8 (round 15) ->
// round 17: uint4 16B/lane loads, 8 edge slots/wave (16 rows in flight).
// deg histogram uses per-XCD replicas (round 16: random atomics on one array
// ping-pong lines across 8 non-coherent L2s; replicas write back once).
// CSR build: bucketed two-phase scatter, 2048 edges/block (rounds 12/13:
// separate hist and small chunks both regressed).
// NOTE (rounds 8+12): XCD dim-sliced gathers failed twice (no L2 residency
// from blockIdx%8->XCD on reads). NOTE (round 10): 64 rows/wave in linear.

typedef _Float16 f16x8 __attribute__((ext_vector_type(8)));
typedef float f32x4 __attribute__((ext_vector_type(4)));

// --- phase A: deg histogram (per-XCD replicas) + bucket (tgt,src) pairs ---
__global__ __launch_bounds__(256) void k_bucket(
    const int* __restrict__ src, const int* __restrict__ tgt,
    int* __restrict__ deg8, unsigned long long* __restrict__ staging,
    int* __restrict__ bucket_fill, int E, int bdiv, int cap, int N) {
  __shared__ unsigned long long buf[8][320];
  __shared__ int cnt[8];
  __shared__ int base[8];
  int tid = threadIdx.x;
  int lane = tid & 63;
  if (tid < 8) cnt[tid] = 0;
  __syncthreads();
  int* degrep = deg8 + (size_t)(blockIdx.x & 7) * N;  // XCD-local replica
  int e0 = blockIdx.x * 2048;
#pragma unroll
  for (int i = 0; i < 8; ++i) {
    int e = e0 + i * 256 + tid;
    int b = -1;
    unsigned long long pair = 0;
    if (e < E) {
      int t = tgt[e];
      int s = src[e];
      atomicAdd(&degrep[t], 1);
      b = t / bdiv;
      pair = ((unsigned long long)(unsigned)t << 32) | (unsigned)s;
    }
#pragma unroll
    for (int bk = 0; bk < 8; ++bk) {
      bool mine = (b == bk);
      unsigned long long mask = __ballot(mine);
      if (mask == 0ull) continue;  // ballot is wave-uniform
      int cw = __popcll(mask);
      int leader = __ffsll((unsigned long long)mask) - 1;
      int p0 = 0;
      if (lane == leader) p0 = atomicAdd(&cnt[bk], cw);
      p0 = __shfl(p0, leader, 64);
      if (mine) {
        int p = p0 + __popcll(mask & ((1ull << lane) - 1ull));
        if (p < 320) {
          buf[bk][p] = pair;
        } else {  // rare overflow: reserve a global slot directly
          int gp = atomicAdd(&bucket_fill[bk], 1);
          staging[(size_t)bk * cap + gp] = pair;
        }
      }
    }
  }
  __syncthreads();
  if (tid < 8) {
    int c = min(cnt[tid], 320);
    base[tid] = atomicAdd(&bucket_fill[tid], c);
    cnt[tid] = c;
  }
  __syncthreads();
  for (int b = 0; b < 8; ++b) {
    int c = cnt[b];
    for (int p = tid; p < c; p += 256)
      staging[(size_t)b * cap + base[b] + p] = buf[b][p];
  }
}

// --- phase B: per-bucket scatter; block g -> bucket g&7 (bucket-local writes) ---
__global__ __launch_bounds__(256) void k_scatter2(
    const unsigned long long* __restrict__ staging,
    const int* __restrict__ bucket_fill, int* __restrict__ cursor,
    int* __restrict__ csr_src, int cap) {
  int b = blockIdx.x & 7;
  int nchunk = gridDim.x >> 3;
  int chunk = blockIdx.x >> 3;
  int n = bucket_fill[b];
  const unsigned long long* sb = staging + (size_t)b * cap;
  for (int i0 = chunk * 2048; i0 < n; i0 += nchunk * 2048) {
#pragma unroll
    for (int t = 0; t < 8; ++t) {
      int i = i0 + t * 256 + (int)threadIdx.x;
      if (i < n) {
        unsigned long long pair = sb[i];
        int tg = (int)(pair >> 32);
        int s = (int)(pair & 0xffffffffu);
        int pos = atomicAdd(&cursor[tg], 1);
        csr_src[pos] = s;
      }
    }
  }
}

// --- parallel exclusive scan; deg = sum of 8 XCD replicas ---
__global__ __launch_bounds__(256) void k_scan1(const int* __restrict__ deg8,
                                               int* __restrict__ partial,
                                               int* __restrict__ blocksum,
                                               float* __restrict__ inv_deg,
                                               int n) {
  __shared__ int s[256];
  int tid = threadIdx.x;
  int i = blockIdx.x * 256 + tid;
  int v = 0;
  if (i < n) {
#pragma unroll
    for (int k = 0; k < 8; ++k) v += deg8[(size_t)k * n + i];
  }
  s[tid] = v;
  __syncthreads();
  for (int off = 1; off < 256; off <<= 1) {
    int t = (tid >= off) ? s[tid - off] : 0;
    __syncthreads();
    s[tid] += t;
    __syncthreads();
  }
  if (i < n) {
    partial[i] = s[tid] - v;
    inv_deg[i] = 1.0f / fmaxf((float)v, 1.0f);
  }
  if (tid == 255) blocksum[blockIdx.x] = s[255];
}

__global__ __launch_bounds__(256) void k_scan2(int* __restrict__ blocksum, int nb) {
  __shared__ int s[256];
  int tid = threadIdx.x;
  int v = (tid < nb) ? blocksum[tid] : 0;
  s[tid] = v;
  __syncthreads();
  for (int off = 1; off < 256; off <<= 1) {
    int t = (tid >= off) ? s[tid - off] : 0;
    __syncthreads();
    s[tid] += t;
    __syncthreads();
  }
  if (tid < nb) blocksum[tid] = s[tid] - v;
}

__global__ __launch_bounds__(256) void k_scan3(const int* __restrict__ partial,
                                               const int* __restrict__ blocksum,
                                               int* __restrict__ row_start,
                                               int* __restrict__ cursor, int n, int E) {
  int i = blockIdx.x * 256 + threadIdx.x;
  if (i < n) {
    int r = partial[i] + blocksum[blockIdx.x];
    row_start[i] = r;
    cursor[i] = r;
  }
  if (i == 0) row_start[n] = E;
}

// x fp32 -> fp16 + fp8 shadow, 8 elements/thread
__global__ __launch_bounds__(256) void k_cvt_x(const float* __restrict__ x,
                                               __half* __restrict__ xh,
                                               unsigned char* __restrict__ xh8,
                                               int total8) {
  int i = blockIdx.x * 256 + threadIdx.x;
  if (i >= total8) return;
  const float4* p = (const float4*)(x + (size_t)i * 8);
  float4 v0 = p[0], v1 = p[1];
  float f[8] = {v0.x, v0.y, v0.z, v0.w, v1.x, v1.y, v1.z, v1.w};
  f16x8 o;
  unsigned long long u8 = 0;
#pragma unroll
  for (int j = 0; j < 8; ++j) {
    o[j] = (_Float16)f[j];
    __hip_fp8_e4m3 q(f[j]);
    u8 |= (unsigned long long)(*reinterpret_cast<unsigned char*>(&q)) << (8 * j);
  }
  *(f16x8*)(xh + (size_t)i * 8) = o;
  *(unsigned long long*)(xh8 + (size_t)i * 8) = u8;
}

struct WPack {
  const float* s[4];
  const float* n[4];
};

// Wt[layer][n][k] (k in [0,256): k<128 -> Ws[k][n], else Wn[k-128][n]), fp16
__global__ __launch_bounds__(256) void k_prep_w(WPack p, __half* __restrict__ Wt) {
  int l = blockIdx.y;
  int i = blockIdx.x * 256 + threadIdx.x;  // [0, 32768)
  int n = i >> 8;
  int k = i & 255;
  const float* W = (k < 128) ? p.s[l] : p.n[l];
  float v = W[(size_t)(k & 127) * 128 + n];
  Wt[(size_t)l * 32768 + (size_t)n * 256 + k] = __float2half(v);
}

// fp8 gather, uint4 width. One wave per node; slot=lane>>3 (8 edge slots),
// lane&7 -> 16 dims (uint4 = 16B -> one 128B row per 8-lane group). x2
// unroll = 16 rows in flight per wave (latency/request-bound: fewer, wider
// loads + deeper MLP). fp8->fp16 decode bit-trick: h16 = sign<<8|expman<<7,
// true value = that x256 (bias 15 vs 7); x256 folded into the 1/deg scale.
// fp16 accumulation (sums <= ~40 x 0.94 — safe). Fold slots shfl_xor(8,16,32).
__global__ __launch_bounds__(256) void k_agg8(
    const unsigned char* __restrict__ h8, const int* __restrict__ csr_src,
    const int* __restrict__ row_start, const float* __restrict__ inv_deg,
    __half* __restrict__ agg, int n_nodes) {
  int gw = (blockIdx.x * 256 + (int)threadIdx.x) >> 6;
  int lane = threadIdx.x & 63;
  if (gw >= n_nodes) return;
  int slot = lane >> 3;       // edge slot 0..7
  int dl = (lane & 7) * 16;   // dims/bytes dl..dl+15
  int beg = row_start[gw];
  int end = row_start[gw + 1];
  __half2 ac[8];
#pragma unroll
  for (int j = 0; j < 8; ++j) ac[j] = __float2half2_rn(0.f);

  auto accum = [&](uint4 w) {
    unsigned v[4] = {w.x, w.y, w.z, w.w};
#pragma unroll
    for (int j = 0; j < 4; ++j) {
      unsigned ev = ((v[j] & 0x00800080u) << 8) | ((v[j] & 0x007f007fu) << 7);
      unsigned od = (((v[j] >> 8) & 0x00800080u) << 8) | (((v[j] >> 8) & 0x007f007fu) << 7);
      ac[2 * j] = __hadd2(ac[2 * j], *reinterpret_cast<__half2*>(&ev));
      ac[2 * j + 1] = __hadd2(ac[2 * j + 1], *reinterpret_cast<__half2*>(&od));
    }
  };

  int e = beg;
  for (; e + 16 <= end; e += 16) {
    int i0 = csr_src[e + slot];
    int i1 = csr_src[e + 8 + slot];
    uint4 w0 = *(const uint4*)(h8 + (size_t)i0 * 128 + dl);
    uint4 w1 = *(const uint4*)(h8 + (size_t)i1 * 128 + dl);
    accum(w0);
    accum(w1);
  }
  for (; e + 8 <= end; e += 8) {
    int i0 = csr_src[e + slot];
    accum(*(const uint4*)(h8 + (size_t)i0 * 128 + dl));
  }
  if (e + slot < end) {
    int i0 = csr_src[e + slot];
    accum(*(const uint4*)(h8 + (size_t)i0 * 128 + dl));
  }
  // fold the 8 edge slots (lanes sharing lane&7 hold identical dim ranges)
#pragma unroll
  for (int off = 8; off <= 32; off <<= 1) {
#pragma unroll
    for (int j = 0; j < 8; ++j) {
      int t = __shfl_xor(*reinterpret_cast<int*>(&ac[j]), off, 64);
      ac[j] = __hadd2(ac[j], *reinterpret_cast<__half2*>(&t));
    }
  }
  if (slot == 0) {
    float wgt = inv_deg[gw] * 256.0f;  // x256 undoes the fp8 decode bias shift
    f16x8 r0, r1;
#pragma unroll
    for (int j = 0; j < 4; ++j) {
      float2 fe = __half22float2(ac[2 * j]);      // dims (4j+0, 4j+2)
      float2 fo = __half22float2(ac[2 * j + 1]);  // dims (4j+1, 4j+3)
      _Float16 d0 = (_Float16)(fe.x * wgt);
      _Float16 d1 = (_Float16)(fo.x * wgt);
      _Float16 d2 = (_Float16)(fe.y * wgt);
      _Float16 d3 = (_Float16)(fo.y * wgt);
      if (j < 2) {
        r0[4 * j] = d0; r0[4 * j + 1] = d1; r0[4 * j + 2] = d2; r0[4 * j + 3] = d3;
      } else {
        r1[4 * (j - 2)] = d0; r1[4 * (j - 2) + 1] = d1;
        r1[4 * (j - 2) + 2] = d2; r1[4 * (j - 2) + 3] = d3;
      }
    }
    *(f16x8*)(agg + (size_t)gw * 128 + dl) = r0;
    *(f16x8*)(agg + (size_t)gw * 128 + dl + 8) = r1;
  }
}

// out[m][n] = relu( h[m]@Ws + agg[m]@Wn + b ), K=256 via mfma_f32_16x16x32_f16.
// Block = 256 threads = 4 waves, 64 rows. Wave w owns col-quarter cq=w (32
// cols) and ALL 64 rows; 16 B-fragments preloaded to registers (Wt L2-hot).
// Epilogue also emits the fp8 e4m3 shadow copy (out8, nullable).
__global__ __launch_bounds__(256) void k_linear_mfma(
    const __half* __restrict__ h, const __half* __restrict__ agg,
    const __half* __restrict__ Wt, const float* __restrict__ bias,
    __half* __restrict__ out, unsigned char* __restrict__ out8, int n_nodes) {
  int tid = threadIdx.x;
  int cq = tid >> 6;  // wave -> col quarter
  int lane = tid & 63;
  int node0 = blockIdx.x * 64;
  int lr = lane & 15;
  int lg = lane >> 4;

  f16x8 bs[8][2];
#pragma unroll
  for (int ks = 0; ks < 8; ++ks) {
    int kb = ks * 32 + lg * 8;
    bs[ks][0] = *(const f16x8*)(Wt + (size_t)(cq * 32 + lr) * 256 + kb);
    bs[ks][1] = *(const f16x8*)(Wt + (size_t)(cq * 32 + 16 + lr) * 256 + kb);
  }

  f32x4 acc[4][2];
#pragma unroll
  for (int rt = 0; rt < 4; ++rt)
#pragma unroll
    for (int ct = 0; ct < 2; ++ct) acc[rt][ct] = (f32x4){0.f, 0.f, 0.f, 0.f};

  const __half* hrow[4];
  const __half* grow[4];
#pragma unroll
  for (int rt = 0; rt < 4; ++rt) {
    int arow = node0 + rt * 16 + lr;
    if (arow >= n_nodes) arow = n_nodes - 1;
    hrow[rt] = h + (size_t)arow * 128;
    grow[rt] = agg + (size_t)arow * 128;
  }

#pragma unroll
  for (int ks = 0; ks < 8; ++ks) {
    int koff = (ks & 3) * 32 + lg * 8;
#pragma unroll
    for (int rt = 0; rt < 4; ++rt) {
      f16x8 a = (ks < 4) ? *(const f16x8*)(hrow[rt] + koff)
                         : *(const f16x8*)(grow[rt] + koff);
      acc[rt][0] = __builtin_amdgcn_mfma_f32_16x16x32_f16(a, bs[ks][0], acc[rt][0], 0, 0, 0);
      acc[rt][1] = __builtin_amdgcn_mfma_f32_16x16x32_f16(a, bs[ks][1], acc[rt][1], 0, 0, 0);
    }
  }

#pragma unroll
  for (int ct = 0; ct < 2; ++ct) {
    int n_col = cq * 32 + ct * 16 + lr;
    float bv = bias[n_col];
#pragma unroll
    for (int rt = 0; rt < 4; ++rt) {
#pragma unroll
      for (int r = 0; r < 4; ++r) {
        int m = node0 + rt * 16 + lg * 4 + r;
        if (m < n_nodes) {
          float v = fmaxf(acc[rt][ct][r] + bv, 0.f);
          out[(size_t)m * 128 + n_col] = __float2half(v);
          if (out8) {
            __hip_fp8_e4m3 q(v);
            out8[(size_t)m * 128 + n_col] = *reinterpret_cast<unsigned char*>(&q);
          }
        }
      }
    }
  }
}

// 256 blocks x 256 threads; wave w handles rows blk*4+w (stride 1024), lane owns
// 2 dims via half2; LDS reduce across the 4 waves -> partial[blk][128].
__global__ __launch_bounds__(256) void k_pool(const __half* __restrict__ h,
                                              float* __restrict__ partial, int n_nodes) {
  __shared__ float red[4][128];
  int tid = threadIdx.x;
  int lane = tid & 63;
  int w = tid >> 6;
  float a0 = 0.f, a1 = 0.f;
  for (int n = blockIdx.x * 4 + w; n < n_nodes; n += gridDim.x * 4) {
    float2 f = __half22float2(*(const __half2*)(h + (size_t)n * 128 + lane * 2));
    a0 += f.x;
    a1 += f.y;
  }
  red[w][lane * 2] = a0;
  red[w][lane * 2 + 1] = a1;
  __syncthreads();
  if (tid < 128) {
    partial[(size_t)blockIdx.x * 128 + tid] =
        (red[0][tid] + red[1][tid]) + (red[2][tid] + red[3][tid]);
  }
}

// 512 threads: chunked parallel reduce of partial[256][128] -> g[128], then
// chunked classifier dot g@Wc[128][64] + bc. Max serial chain: 64 loads.
__global__ __launch_bounds__(512) void k_final(const float* __restrict__ partial,
                                               const float* __restrict__ Wc,
                                               const float* __restrict__ bc,
                                               float* __restrict__ out, int n_nodes) {
  __shared__ float red[4][128];
  __shared__ float gs[128];
  __shared__ float red2[8][64];
  int tid = threadIdx.x;
  int j = tid & 127;
  int c = tid >> 7;  // 4 chunks of 64 partials
  float s = 0.f;
#pragma unroll
  for (int b = 0; b < 64; ++b) s += partial[(size_t)(c * 64 + b) * 128 + j];
  red[c][j] = s;
  __syncthreads();
  if (tid < 128) {
    float g = (red[0][tid] + red[1][tid]) + (red[2][tid] + red[3][tid]);
    gs[tid] = g / (float)n_nodes;
  }
  __syncthreads();
  {
    int jo = tid & 63;
    int c2 = tid >> 6;  // 8 chunks of 16 k
    float s2 = 0.f;
#pragma unroll
    for (int d = 0; d < 16; ++d)
      s2 += gs[c2 * 16 + d] * Wc[(size_t)(c2 * 16 + d) * 64 + jo];
    red2[c2][jo] = s2;
  }
  __syncthreads();
  if (tid < 64) {
    float o = bc[tid];
#pragma unroll
    for (int c2 = 0; c2 < 8; ++c2) o += red2[c2][tid];
    out[tid] = o;
  }
}

extern "C" void kernel_launch(void* const* d_in, const int* in_sizes, int n_in,
                              void* d_out, int out_size, void* d_ws, size_t ws_size,
                              hipStream_t stream) {
  const float* x = (const float*)d_in[0];
  const int* ei = (const int*)d_in[1];
  const float* Ws11 = (const float*)d_in[2];
  const float* Wn11 = (const float*)d_in[3];
  const float* b11 = (const float*)d_in[4];
  const float* Ws12 = (const float*)d_in[5];
  const float* Wn12 = (const float*)d_in[6];
  const float* b12 = (const float*)d_in[7];
  const float* Ws21 = (const float*)d_in[8];
  const float* Wn21 = (const float*)d_in[9];
  const float* b21 = (const float*)d_in[10];
  const float* Ws22 = (const float*)d_in[11];
  const float* Wn22 = (const float*)d_in[12];
  const float* b22 = (const float*)d_in[13];
  const float* Wc = (const float*)d_in[14];
  const float* bc = (const float*)d_in[15];

  int N = in_sizes[0] / 128;
  int E = in_sizes[1] / 2;
  const int* src = ei;
  const int* tgt = ei + E;

  int bdiv = (N + 7) / 8;        // bucket = tgt / bdiv, 0..7
  int cap = E / 8 + 8192;        // per-bucket staging capacity

  // workspace layout (256B-aligned chunks)
  char* w = (char*)d_ws;
  size_t off = 0;
  auto alloc = [&](size_t bytes) {
    void* p = w + off;
    off += (bytes + 255) & ~(size_t)255;
    return p;
  };
  __half* xh = (__half*)alloc((size_t)N * 128 * 2);
  __half* hA = (__half*)alloc((size_t)N * 128 * 2);
  __half* hB = (__half*)alloc((size_t)N * 128 * 2);
  __half* aggb = (__half*)alloc((size_t)N * 128 * 2);
  unsigned char* xh8 = (unsigned char*)alloc((size_t)N * 128);
  unsigned char* h8A = (unsigned char*)alloc((size_t)N * 128);
  unsigned char* h8B = (unsigned char*)alloc((size_t)N * 128);
  __half* Wt = (__half*)alloc((size_t)4 * 32768 * 2);
  float* inv_deg = (float*)alloc((size_t)N * 4);
  // --- zeroed region: deg8 | bucket_fill | partial (contiguous, one memset) ---
  size_t zbase = off;
  int* deg8 = (int*)alloc((size_t)8 * N * 4);   // per-XCD replicas
  int* bucket_fill = (int*)alloc((size_t)8 * 4);
  float* partial = (float*)alloc((size_t)256 * 128 * 4);
  size_t zbytes = off - zbase;
  int* row_start = (int*)alloc((size_t)(N + 1) * 4);
  int* cursor = (int*)alloc((size_t)N * 4);
  int* csr_src = (int*)alloc((size_t)E * 4);
  int* scanp = (int*)alloc((size_t)N * 4);
  int* blocksum = (int*)alloc((size_t)256 * 4);
  unsigned long long* staging =
      (unsigned long long*)alloc((size_t)8 * cap * 8);

  hipMemsetAsync((char*)d_ws + zbase, 0, zbytes, stream);

  int nb = (N + 255) / 256;
  int bb = (E + 2047) / 2048;
  k_bucket<<<bb, 256, 0, stream>>>(src, tgt, deg8, staging, bucket_fill, E, bdiv, cap, N);
  k_scan1<<<nb, 256, 0, stream>>>(deg8, scanp, blocksum, inv_deg, N);
  k_scan2<<<1, 256, 0, stream>>>(blocksum, nb);
  k_scan3<<<nb, 256, 0, stream>>>(scanp, blocksum, row_start, cursor, N, E);
  k_scatter2<<<448, 256, 0, stream>>>(staging, bucket_fill, cursor, csr_src, cap);

  int total8 = N * 128 / 8;
  int cb = (total8 + 255) / 256;
  k_cvt_x<<<cb, 256, 0, stream>>>(x, xh, xh8, total8);
  WPack wp;
  wp.s[0] = Ws11; wp.s[1] = Ws12; wp.s[2] = Ws21; wp.s[3] = Ws22;
  wp.n[0] = Wn11; wp.n[1] = Wn12; wp.n[2] = Wn21; wp.n[3] = Wn22;
  k_prep_w<<<dim3(128, 4), 256, 0, stream>>>(wp, Wt);

  int ab = (N + 3) / 4;     // k_agg8: 4 waves/block, 1 node/wave
  int lb = (N + 63) / 64;   // k_linear_mfma: 64 rows/block

  // layer 1: xh -> hA (+h8A)
  k_agg8<<<ab, 256, 0, stream>>>(xh8, csr_src, row_start, inv_deg, aggb, N);
  k_linear_mfma<<<lb, 256, 0, stream>>>(xh, aggb, Wt + 0 * 32768, b11, hA, h8A, N);
  // layer 2: hA -> hB (+h8B)
  k_agg8<<<ab, 256, 0, stream>>>(h8A, csr_src, row_start, inv_deg, aggb, N);
  k_linear_mfma<<<lb, 256, 0, stream>>>(hA, aggb, Wt + 1 * 32768, b12, hB, h8B, N);
  // layer 3: hB -> hA (+h8A)
  k_agg8<<<ab, 256, 0, stream>>>(h8B, csr_src, row_start, inv_deg, aggb, N);
  k_linear_mfma<<<lb, 256, 0, stream>>>(hB, aggb, Wt + 2 * 32768, b21, hA, h8A, N);
  // layer 4: hA -> hB (no fp8 needed)
  k_agg8<<<ab, 256, 0, stream>>>(h8A, csr_src, row_start, inv_deg, aggb, N);
  k_linear_mfma<<<lb, 256, 0, stream>>>(hA, aggb, Wt + 3 * 32768, b22, hB, (unsigned char*)nullptr, N);

  k_pool<<<256, 256, 0, stream>>>(hB, partial, N);
  k_final<<<1, 512, 0, stream>>>(partial, Wc, bc, (float*)d_out, N);
}